// Round 3
// baseline (7616.302 us; speedup 1.0000x reference)
//
#include <hip/hip_runtime.h>
#include <math.h>

// Problem constants
#define D      128
#define NQ     512          // B * LQ = 4 * 128
#define LCTX   65536
#define TOPN   8
#define NCAND  16           // coarse candidates refined in f64
// Distance-kernel tiling
#define QT     64           // queries per block
#define CT     64           // contexts per LDS sub-tile
#define CCHUNK 1024         // contexts per block
#define NCH    (LCTX / CCHUNK)   // 64 chunks
#define NQT    (NQ / QT)         // 8 query tiles
#define FINF   3.0e38f

// ---------------------------------------------------------------------------
// Kernel 1: ||c||^2 for every context position (coarse fp32 rank key input).
__global__ __launch_bounds__(256) void cn2_kernel(const int* __restrict__ ctok,
                                                  const float* __restrict__ emb,
                                                  float* __restrict__ cn2) {
  const int g = threadIdx.x >> 5, l = threadIdx.x & 31;
  const int row = blockIdx.x * 8 + g;
  const int tok = ctok[row];
  const float4 v = *(const float4*)(emb + (size_t)tok * D + 4 * l);
  float p = v.x * v.x + v.y * v.y + v.z * v.z + v.w * v.w;
#pragma unroll
  for (int off = 16; off; off >>= 1) p += __shfl_xor(p, off, 32);
  if (l == 0) cn2[row] = p;
}

// ---------------------------------------------------------------------------
// Kernel 2: qp = q @ W + b.  One block (128 thr) per query.
__global__ __launch_bounds__(128) void qprep_kernel(const int* __restrict__ qtok,
                                                    const float* __restrict__ emb,
                                                    const float* __restrict__ W,
                                                    const float* __restrict__ bvec,
                                                    float* __restrict__ qp) {
  const int q = blockIdx.x;
  const int d = threadIdx.x;  // 0..127
  __shared__ float sq[D];
  const int tok = qtok[q];
  sq[d] = emb[(size_t)tok * D + d];
  __syncthreads();
  float acc = bvec[d];
  for (int k = 0; k < D; ++k) acc = fmaf(sq[k], W[k * D + d], acc);
  qp[(size_t)q * D + d] = acc;
}

// ---------------------------------------------------------------------------
// Kernel 3: coarse distances + streaming top-8 per (query, chunk).
// Grid (NCH, NQT), 256 threads. LDS: swizzled Q tile (64x128f) + C tile (64x128f).
// LDS slot k of row r holds global chunk k ^ s(r), s(r) = (r>>2)&7; the
// permutation is applied on the *global read* so LDS writes are lane-linear.
__global__ __launch_bounds__(256, 2) void dist_topk_kernel(
    const int* __restrict__ ctok, const int* __restrict__ qtok,
    const float* __restrict__ emb, const float* __restrict__ cn2,
    float2* __restrict__ partials) {
  __shared__ __align__(16) float smem[QT * D + CT * D];  // 65536 B
  float* sQ = smem;
  float* sC = smem + QT * D;

  const int tid = threadIdx.x;
  const int tx = tid & 15, ty = tid >> 4;   // 16 x 16 thread grid
  const int g = tid >> 5, l = tid & 31;     // staging: 8 groups of 32 lanes
  const int chunk = blockIdx.x, qtile = blockIdx.y;
  const int qbase = qtile * QT, cbase0 = chunk * CCHUNK;

  // ---- stage Q tile (once); swizzle applied on global-read side ----
#pragma unroll
  for (int rr = 0; rr < 8; ++rr) {
    const int row = rr * 8 + g;
    const int tok = qtok[qbase + row];
    const int s = (row >> 2) & 7;
    const float4 v = *(const float4*)(emb + (size_t)tok * D + 4 * (l ^ s));
    *(float4*)(sQ + row * D + 4 * l) = v;
  }

  // ---- per-thread top-8 state: 4 query rows x 8 slots ----
  float bs[4][8];
  int bi[4][8];
  float bmax[4];
#pragma unroll
  for (int i = 0; i < 4; ++i) {
    bmax[i] = FINF;
#pragma unroll
    for (int t = 0; t < 8; ++t) { bs[i][t] = FINF; bi[i][t] = 0; }
  }

  // Q slot kp holds chunk kp^(ty&7); chunk kp^(ty&7) sits in C slot
  // kp^(ty&7)^(tx&7).  h = (ty^tx)&7  (bitwise: (ty&7)^(tx&7)).
  const int h = (ty ^ tx) & 7;

  for (int st = 0; st < CCHUNK / CT; ++st) {
    const int cb = cbase0 + st * CT;
    __syncthreads();
    int toks[8];
#pragma unroll
    for (int rr = 0; rr < 8; ++rr) toks[rr] = ctok[cb + rr * 8 + g];
    float4 vals[8];
#pragma unroll
    for (int rr = 0; rr < 8; ++rr) {
      const int row = rr * 8 + g;
      const int s = (row >> 2) & 7;
      vals[rr] = *(const float4*)(emb + (size_t)toks[rr] * D + 4 * (l ^ s));
    }
#pragma unroll
    for (int rr = 0; rr < 8; ++rr) {
      const int row = rr * 8 + g;
      *(float4*)(sC + row * D + 4 * l) = vals[rr];
    }
    __syncthreads();

    const float4 cn2v = *(const float4*)(cn2 + cb + 4 * tx);
    float cn2a[4] = {cn2v.x, cn2v.y, cn2v.z, cn2v.w};

    float acc[4][4];
#pragma unroll
    for (int i = 0; i < 4; ++i)
#pragma unroll
      for (int j = 0; j < 4; ++j) acc[i][j] = 0.f;

#pragma unroll
    for (int kp = 0; kp < 32; ++kp) {
      float4 qv[4], cv[4];
      const int oc = (kp ^ h) << 2;
#pragma unroll
      for (int i = 0; i < 4; ++i) qv[i] = *(const float4*)(sQ + (4 * ty + i) * D + 4 * kp);
#pragma unroll
      for (int j = 0; j < 4; ++j) cv[j] = *(const float4*)(sC + (4 * tx + j) * D + oc);
#pragma unroll
      for (int i = 0; i < 4; ++i)
#pragma unroll
        for (int j = 0; j < 4; ++j)
          acc[i][j] += qv[i].x * cv[j].x + qv[i].y * cv[j].y +
                       qv[i].z * cv[j].z + qv[i].w * cv[j].w;
    }

    // ---- selection: rank key s = ||c||^2 - 2 q.c (monotone in dist) ----
#pragma unroll
    for (int i = 0; i < 4; ++i) {
#pragma unroll
      for (int j = 0; j < 4; ++j) {
        const float s = fmaf(-2.f, acc[i][j], cn2a[j]);
        if (s < bmax[i]) {
          const int idx = cb + 4 * tx + j;
          bool done = false;
#pragma unroll
          for (int t = 0; t < 8; ++t) {
            const bool hit = (!done) && (bs[i][t] == bmax[i]);
            if (hit) { bs[i][t] = s; bi[i][t] = idx; done = true; }
          }
          float m = bs[i][0];
#pragma unroll
          for (int t = 1; t < 8; ++t) m = fmaxf(m, bs[i][t]);
          bmax[i] = m;
        }
      }
    }
  }

  // ---- block-level merge: 16 threads x 8 slots -> 8 per (query, chunk) ----
  __syncthreads();
  float2* mb = (float2*)smem;
#pragma unroll
  for (int i = 0; i < 4; ++i) {
    const int qrow = 4 * ty + i;
#pragma unroll
    for (int t = 0; t < 8; ++t)
      mb[qrow * 128 + tx * 8 + t] = make_float2(bs[i][t], __int_as_float(bi[i][t]));
  }
  __syncthreads();
  if (tid < QT) {
    const int qrow = tid;
    float ts[8]; int ti8[8]; float tmax = FINF;
#pragma unroll
    for (int t = 0; t < 8; ++t) { ts[t] = FINF; ti8[t] = 0; }
    for (int c = 0; c < 128; ++c) {
      const float2 cd = mb[qrow * 128 + c];
      if (cd.x < tmax) {
        bool done = false;
#pragma unroll
        for (int t = 0; t < 8; ++t) {
          const bool hit = (!done) && (ts[t] == tmax);
          if (hit) { ts[t] = cd.x; ti8[t] = __float_as_int(cd.y); done = true; }
        }
        float m = ts[0];
#pragma unroll
        for (int t = 1; t < 8; ++t) m = fmaxf(m, ts[t]);
        tmax = m;
      }
    }
    const int q = qbase + qrow;
#pragma unroll
    for (int t = 0; t < 8; ++t)
      partials[(size_t)(chunk * 8 + t) * NQ + q] = make_float2(ts[t], __int_as_float(ti8[t]));
  }
}

// ---------------------------------------------------------------------------
// Kernel 4: per-query coarse merge of 512 candidates -> top-16 indices.
__global__ __launch_bounds__(64) void merge16_kernel(const float2* __restrict__ partials,
                                                     int* __restrict__ cand) {
  const int q = blockIdx.x * 64 + threadIdx.x;
  float ts[NCAND]; int ti[NCAND]; float tmax = FINF;
#pragma unroll
  for (int t = 0; t < NCAND; ++t) { ts[t] = FINF; ti[t] = 0; }
  for (int c = 0; c < NCH * 8; ++c) {
    const float2 cd = partials[(size_t)c * NQ + q];  // coalesced across lanes
    if (cd.x < tmax) {
      bool done = false;
#pragma unroll
      for (int t = 0; t < NCAND; ++t) {
        const bool hit = (!done) && (ts[t] == tmax);
        if (hit) { ts[t] = cd.x; ti[t] = __float_as_int(cd.y); done = true; }
      }
      float m = ts[0];
#pragma unroll
      for (int t = 1; t < NCAND; ++t) m = fmaxf(m, ts[t]);
      tmax = m;
    }
  }
#pragma unroll
  for (int t = 0; t < NCAND; ++t) cand[q * NCAND + t] = ti[t];
}

// ---------------------------------------------------------------------------
// Kernel 5: f64 refine — exact d^2 = sum (q-c)^2 and dp = qp.c per (q, cand).
// One 32-lane group per pair; one float4 per lane spans all 128 dims.
__global__ __launch_bounds__(256) void refine_kernel(const int* __restrict__ cand,
                                                     const int* __restrict__ qtok,
                                                     const int* __restrict__ ctok,
                                                     const float* __restrict__ emb,
                                                     const float* __restrict__ qp,
                                                     double* __restrict__ rd2,
                                                     double* __restrict__ rdp) {
  const int g = threadIdx.x >> 5, l = threadIdx.x & 31;
  const int p = blockIdx.x * 8 + g;          // 0 .. NQ*NCAND-1
  const int q = p >> 4, n = p & (NCAND - 1);
  const int idx = cand[q * NCAND + n];
  const int tc = ctok[idx], tq = qtok[q];
  const float4 c4 = *(const float4*)(emb + (size_t)tc * D + 4 * l);
  const float4 q4 = *(const float4*)(emb + (size_t)tq * D + 4 * l);
  const float4 p4 = *(const float4*)(qp + (size_t)q * D + 4 * l);
  const double dx = (double)q4.x - (double)c4.x, dy = (double)q4.y - (double)c4.y;
  const double dz = (double)q4.z - (double)c4.z, dw = (double)q4.w - (double)c4.w;
  double dd = dx * dx + dy * dy + dz * dz + dw * dw;
  double pp = (double)p4.x * (double)c4.x + (double)p4.y * (double)c4.y +
              (double)p4.z * (double)c4.z + (double)p4.w * (double)c4.w;
#pragma unroll
  for (int off = 16; off; off >>= 1) {
    dd += __shfl_xor(dd, off, 32);
    pp += __shfl_xor(pp, off, 32);
  }
  if (l == 0) { rd2[q * NCAND + n] = dd; rdp[q * NCAND + n] = pp; }
}

// ---------------------------------------------------------------------------
// Kernel 6: exact top-8 of 16 by f64 d^2, logits + softmax-max (f64).
__global__ __launch_bounds__(64) void final_kernel(const double* __restrict__ rd2,
                                                   const double* __restrict__ rdp,
                                                   const int* __restrict__ cand,
                                                   float* __restrict__ importance) {
  const int q = blockIdx.x * 64 + threadIdx.x;
  double d2[NCAND], dp[NCAND]; int id[NCAND]; bool used[NCAND];
#pragma unroll
  for (int n = 0; n < NCAND; ++n) {
    d2[n] = rd2[q * NCAND + n];
    dp[n] = rdp[q * NCAND + n];
    id[n] = cand[q * NCAND + n];
    used[n] = false;
  }
  double lg[TOPN];
  for (int t = 0; t < TOPN; ++t) {
    int best = -1;
    for (int n = 0; n < NCAND; ++n) {
      if (used[n]) continue;
      if (best < 0 || d2[n] < d2[best] ||
          (d2[n] == d2[best] && id[n] < id[best])) best = n;
    }
    used[best] = true;
    lg[t] = dp[best] * 0.08838834764831843 - sqrt(d2[best] + 1e-12);
  }
  double m = lg[0];
#pragma unroll
  for (int t = 1; t < TOPN; ++t) m = fmax(m, lg[t]);
  double sum = 0.0;
#pragma unroll
  for (int t = 0; t < TOPN; ++t) sum += exp(lg[t] - m);
  importance[q] = (float)(1.0 / sum);  // max softmax = 1/sum
}

// ---------------------------------------------------------------------------
// Kernel 7: softmax over Lq per batch, write reconstructed query (f64 internal).
__global__ __launch_bounds__(128) void out_kernel(const float* __restrict__ importance,
                                                  const int* __restrict__ qtok,
                                                  float* __restrict__ out) {
  const int b = blockIdx.x, i = threadIdx.x;  // 4 blocks x 128 threads
  __shared__ double sred[2];
  const double v = (double)importance[b * 128 + i];
  double m = v;
#pragma unroll
  for (int off = 32; off; off >>= 1) m = fmax(m, __shfl_xor(m, off, 64));
  if ((i & 63) == 0) sred[i >> 6] = m;
  __syncthreads();
  const double M = fmax(sred[0], sred[1]);
  const double e = exp(v - M);
  double s = e;
#pragma unroll
  for (int off = 32; off; off >>= 1) s += __shfl_xor(s, off, 64);
  __syncthreads();
  if ((i & 63) == 0) sred[i >> 6] = s;
  __syncthreads();
  const double S = sred[0] + sred[1];
  out[b * 128 + i] = (float)((double)qtok[b * 128 + i] * (e / S) * 128.0);
}

// ---------------------------------------------------------------------------
extern "C" void kernel_launch(void* const* d_in, const int* in_sizes, int n_in,
                              void* d_out, int out_size, void* d_ws, size_t ws_size,
                              hipStream_t stream) {
  const int* qtok = (const int*)d_in[0];
  const int* ctok = (const int*)d_in[1];
  const float* emb = (const float*)d_in[2];
  const float* W = (const float*)d_in[3];
  const float* bvec = (const float*)d_in[4];
  float* out = (float*)d_out;

  char* ws = (char*)d_ws;
  double* rd2 = (double*)ws;                       // 64 KB (8B-aligned first)
  double* rdp = rd2 + NQ * NCAND;                  // 64 KB
  float* cn2 = (float*)(rdp + NQ * NCAND);         // 256 KB
  float* qp = cn2 + LCTX;                          // 256 KB
  float* imp = qp + (size_t)NQ * D;                // 2 KB
  int* cand = (int*)(imp + NQ);                    // 32 KB
  float2* partials = (float2*)(cand + NQ * NCAND); // 2 MB

  cn2_kernel<<<LCTX / 8, 256, 0, stream>>>(ctok, emb, cn2);
  qprep_kernel<<<NQ, 128, 0, stream>>>(qtok, emb, W, bvec, qp);
  dist_topk_kernel<<<dim3(NCH, NQT), 256, 0, stream>>>(ctok, qtok, emb, cn2, partials);
  merge16_kernel<<<NQ / 64, 64, 0, stream>>>(partials, cand);
  refine_kernel<<<NQ * NCAND / 8, 256, 0, stream>>>(cand, qtok, ctok, emb, qp, rd2, rdp);
  final_kernel<<<NQ / 64, 64, 0, stream>>>(rd2, rdp, cand, imp);
  out_kernel<<<4, 128, 0, stream>>>(imp, qtok, out);
}

// Round 4
// 7438.686 us; speedup vs baseline: 1.0239x; 1.0239x over previous
//
#include <hip/hip_runtime.h>
#include <math.h>

// Problem constants
#define D      128
#define NQ     512          // B * LQ = 4 * 128
#define LCTX   65536
#define TOPN   8
#define NCAND  16           // coarse candidates refined in f64
// Distance-kernel tiling
#define QT     64           // queries per block
#define CT     64           // contexts per LDS sub-tile
#define CCHUNK 1024         // contexts per block
#define NCH    (LCTX / CCHUNK)   // 64 chunks
#define NQT    (NQ / QT)         // 8 query tiles
#define FINF   3.0e38f

// ---------------------------------------------------------------------------
// Kernel 1: ||c||^2 for every context position (coarse fp32 rank key input).
__global__ __launch_bounds__(256) void cn2_kernel(const int* __restrict__ ctok,
                                                  const float* __restrict__ emb,
                                                  float* __restrict__ cn2) {
  const int g = threadIdx.x >> 5, l = threadIdx.x & 31;
  const int row = blockIdx.x * 8 + g;
  const int tok = ctok[row];
  const float4 v = *(const float4*)(emb + (size_t)tok * D + 4 * l);
  float p = v.x * v.x + v.y * v.y + v.z * v.z + v.w * v.w;
#pragma unroll
  for (int off = 16; off; off >>= 1) p += __shfl_xor(p, off, 32);
  if (l == 0) cn2[row] = p;
}

// ---------------------------------------------------------------------------
// Kernel 2: qp = q @ W + b.  One block (128 thr) per query.
__global__ __launch_bounds__(128) void qprep_kernel(const int* __restrict__ qtok,
                                                    const float* __restrict__ emb,
                                                    const float* __restrict__ W,
                                                    const float* __restrict__ bvec,
                                                    float* __restrict__ qp) {
  const int q = blockIdx.x;
  const int d = threadIdx.x;  // 0..127
  __shared__ float sq[D];
  const int tok = qtok[q];
  sq[d] = emb[(size_t)tok * D + d];
  __syncthreads();
  float acc = bvec[d];
  for (int k = 0; k < D; ++k) acc = fmaf(sq[k], W[k * D + d], acc);
  qp[(size_t)q * D + d] = acc;
}

// ---------------------------------------------------------------------------
// Kernel 3: coarse distances + streaming top-8 per (query, chunk).
// Grid (NCH, NQT), 512 threads, 2q x 4c micro-tile (register demand ~90 VGPR:
// R3 post-mortem showed the 4q x 4c / 256-thread version spilled acc to
// scratch at the compiler's 128-VGPR target -> 19 GB of HBM spill traffic).
// LDS slot k of row r holds global chunk k ^ s(r), s(r) = (r>>2)&7; the
// permutation is applied on the *global read* so LDS writes are lane-linear.
__global__ __launch_bounds__(512) void dist_topk_kernel(
    const int* __restrict__ ctok, const int* __restrict__ qtok,
    const float* __restrict__ emb, const float* __restrict__ cn2,
    float2* __restrict__ partials) {
  __shared__ __align__(16) float smem[QT * D + CT * D];  // 65536 B
  float* sQ = smem;
  float* sC = smem + QT * D;

  const int tid = threadIdx.x;
  const int tx = tid & 15;        // 16 cols of 4 contexts = 64
  const int tyy = tid >> 4;       // 32 rows of 2 queries  = 64
  const int g = tid >> 5, l = tid & 31;  // staging: 16 groups of 32 lanes
  const int chunk = blockIdx.x, qtile = blockIdx.y;
  const int qbase = qtile * QT, cbase0 = chunk * CCHUNK;

  // ---- stage Q tile (once); swizzle applied on global-read side ----
#pragma unroll
  for (int rr = 0; rr < 4; ++rr) {
    const int row = rr * 16 + g;
    const int tok = qtok[qbase + row];
    const int s = (row >> 2) & 7;
    const float4 v = *(const float4*)(emb + (size_t)tok * D + 4 * (l ^ s));
    *(float4*)(sQ + row * D + 4 * l) = v;
  }

  // ---- per-thread top-8 state: 2 query rows x 8 slots ----
  float bs[2][8];
  int bi[2][8];
  float bmax[2];
#pragma unroll
  for (int i = 0; i < 2; ++i) {
    bmax[i] = FINF;
#pragma unroll
    for (int t = 0; t < 8; ++t) { bs[i][t] = FINF; bi[i][t] = 0; }
  }

  // Q slot kp of row 2*tyy+i holds chunk kp ^ s_q, s_q = ((2*tyy+i)>>2)&7
  // = (tyy>>1)&7 (i<2).  That chunk sits in C slot kp ^ s_q ^ s_c with
  // s_c = (tx&7).  h = ((tyy>>1) ^ tx) & 7.
  const int h = ((tyy >> 1) ^ tx) & 7;

  for (int st = 0; st < CCHUNK / CT; ++st) {
    const int cb = cbase0 + st * CT;
    __syncthreads();
    // ---- stage C sub-tile: 16 groups x 4 rows ----
    int toks[4];
#pragma unroll
    for (int rr = 0; rr < 4; ++rr) toks[rr] = ctok[cb + rr * 16 + g];
    float4 vals[4];
#pragma unroll
    for (int rr = 0; rr < 4; ++rr) {
      const int row = rr * 16 + g;
      const int s = (row >> 2) & 7;
      vals[rr] = *(const float4*)(emb + (size_t)toks[rr] * D + 4 * (l ^ s));
    }
#pragma unroll
    for (int rr = 0; rr < 4; ++rr) {
      const int row = rr * 16 + g;
      *(float4*)(sC + row * D + 4 * l) = vals[rr];
    }
    __syncthreads();

    const float4 cn2v = *(const float4*)(cn2 + cb + 4 * tx);
    float cn2a[4] = {cn2v.x, cn2v.y, cn2v.z, cn2v.w};

    float acc[2][4];
#pragma unroll
    for (int i = 0; i < 2; ++i)
#pragma unroll
      for (int j = 0; j < 4; ++j) acc[i][j] = 0.f;

#pragma unroll
    for (int kp = 0; kp < 32; ++kp) {
      float4 qv[2], cv[4];
      const int oc = (kp ^ h) << 2;
#pragma unroll
      for (int i = 0; i < 2; ++i) qv[i] = *(const float4*)(sQ + (2 * tyy + i) * D + 4 * kp);
#pragma unroll
      for (int j = 0; j < 4; ++j) cv[j] = *(const float4*)(sC + (4 * tx + j) * D + oc);
#pragma unroll
      for (int i = 0; i < 2; ++i)
#pragma unroll
        for (int j = 0; j < 4; ++j)
          acc[i][j] += qv[i].x * cv[j].x + qv[i].y * cv[j].y +
                       qv[i].z * cv[j].z + qv[i].w * cv[j].w;
    }

    // ---- selection: rank key s = ||c||^2 - 2 q.c (monotone in dist) ----
#pragma unroll
    for (int i = 0; i < 2; ++i) {
#pragma unroll
      for (int j = 0; j < 4; ++j) {
        const float s = fmaf(-2.f, acc[i][j], cn2a[j]);
        if (s < bmax[i]) {
          const int idx = cb + 4 * tx + j;
          bool done = false;
#pragma unroll
          for (int t = 0; t < 8; ++t) {
            const bool hit = (!done) && (bs[i][t] == bmax[i]);
            if (hit) { bs[i][t] = s; bi[i][t] = idx; done = true; }
          }
          float m = bs[i][0];
#pragma unroll
          for (int t = 1; t < 8; ++t) m = fmaxf(m, bs[i][t]);
          bmax[i] = m;
        }
      }
    }
  }

  // ---- block-level merge: 16 threads x 8 slots -> 8 per (query, chunk) ----
  __syncthreads();
  float2* mb = (float2*)smem;  // [QT][128] candidates = 65536 B, reuses tiles
#pragma unroll
  for (int i = 0; i < 2; ++i) {
    const int qrow = 2 * tyy + i;
#pragma unroll
    for (int t = 0; t < 8; ++t)
      mb[qrow * 128 + tx * 8 + t] = make_float2(bs[i][t], __int_as_float(bi[i][t]));
  }
  __syncthreads();
  if (tid < QT) {
    const int qrow = tid;
    float ts[8]; int ti8[8]; float tmax = FINF;
#pragma unroll
    for (int t = 0; t < 8; ++t) { ts[t] = FINF; ti8[t] = 0; }
    for (int c = 0; c < 128; ++c) {
      const float2 cd = mb[qrow * 128 + c];
      if (cd.x < tmax) {
        bool done = false;
#pragma unroll
        for (int t = 0; t < 8; ++t) {
          const bool hit = (!done) && (ts[t] == tmax);
          if (hit) { ts[t] = cd.x; ti8[t] = __float_as_int(cd.y); done = true; }
        }
        float m = ts[0];
#pragma unroll
        for (int t = 1; t < 8; ++t) m = fmaxf(m, ts[t]);
        tmax = m;
      }
    }
    const int q = qbase + qrow;
#pragma unroll
    for (int t = 0; t < 8; ++t)
      partials[(size_t)(chunk * 8 + t) * NQ + q] = make_float2(ts[t], __int_as_float(ti8[t]));
  }
}

// ---------------------------------------------------------------------------
// Kernel 4: per-query coarse merge of 512 candidates -> top-16 indices.
__global__ __launch_bounds__(64) void merge16_kernel(const float2* __restrict__ partials,
                                                     int* __restrict__ cand) {
  const int q = blockIdx.x * 64 + threadIdx.x;
  float ts[NCAND]; int ti[NCAND]; float tmax = FINF;
#pragma unroll
  for (int t = 0; t < NCAND; ++t) { ts[t] = FINF; ti[t] = 0; }
  for (int c = 0; c < NCH * 8; ++c) {
    const float2 cd = partials[(size_t)c * NQ + q];  // coalesced across lanes
    if (cd.x < tmax) {
      bool done = false;
#pragma unroll
      for (int t = 0; t < NCAND; ++t) {
        const bool hit = (!done) && (ts[t] == tmax);
        if (hit) { ts[t] = cd.x; ti[t] = __float_as_int(cd.y); done = true; }
      }
      float m = ts[0];
#pragma unroll
      for (int t = 1; t < NCAND; ++t) m = fmaxf(m, ts[t]);
      tmax = m;
    }
  }
#pragma unroll
  for (int t = 0; t < NCAND; ++t) cand[q * NCAND + t] = ti[t];
}

// ---------------------------------------------------------------------------
// Kernel 5: f64 refine — exact d^2 = sum (q-c)^2 and dp = qp.c per (q, cand).
// One 32-lane group per pair; one float4 per lane spans all 128 dims.
__global__ __launch_bounds__(256) void refine_kernel(const int* __restrict__ cand,
                                                     const int* __restrict__ qtok,
                                                     const int* __restrict__ ctok,
                                                     const float* __restrict__ emb,
                                                     const float* __restrict__ qp,
                                                     double* __restrict__ rd2,
                                                     double* __restrict__ rdp) {
  const int g = threadIdx.x >> 5, l = threadIdx.x & 31;
  const int p = blockIdx.x * 8 + g;          // 0 .. NQ*NCAND-1
  const int q = p >> 4, n = p & (NCAND - 1);
  const int idx = cand[q * NCAND + n];
  const int tc = ctok[idx], tq = qtok[q];
  const float4 c4 = *(const float4*)(emb + (size_t)tc * D + 4 * l);
  const float4 q4 = *(const float4*)(emb + (size_t)tq * D + 4 * l);
  const float4 p4 = *(const float4*)(qp + (size_t)q * D + 4 * l);
  const double dx = (double)q4.x - (double)c4.x, dy = (double)q4.y - (double)c4.y;
  const double dz = (double)q4.z - (double)c4.z, dw = (double)q4.w - (double)c4.w;
  double dd = dx * dx + dy * dy + dz * dz + dw * dw;
  double pp = (double)p4.x * (double)c4.x + (double)p4.y * (double)c4.y +
              (double)p4.z * (double)c4.z + (double)p4.w * (double)c4.w;
#pragma unroll
  for (int off = 16; off; off >>= 1) {
    dd += __shfl_xor(dd, off, 32);
    pp += __shfl_xor(pp, off, 32);
  }
  if (l == 0) { rd2[q * NCAND + n] = dd; rdp[q * NCAND + n] = pp; }
}

// ---------------------------------------------------------------------------
// Kernel 6: exact top-8 of 16 by f64 d^2, logits + softmax-max (f64).
__global__ __launch_bounds__(64) void final_kernel(const double* __restrict__ rd2,
                                                   const double* __restrict__ rdp,
                                                   const int* __restrict__ cand,
                                                   float* __restrict__ importance) {
  const int q = blockIdx.x * 64 + threadIdx.x;
  double d2[NCAND], dp[NCAND]; int id[NCAND]; bool used[NCAND];
#pragma unroll
  for (int n = 0; n < NCAND; ++n) {
    d2[n] = rd2[q * NCAND + n];
    dp[n] = rdp[q * NCAND + n];
    id[n] = cand[q * NCAND + n];
    used[n] = false;
  }
  double lg[TOPN];
  for (int t = 0; t < TOPN; ++t) {
    int best = -1;
    for (int n = 0; n < NCAND; ++n) {
      if (used[n]) continue;
      if (best < 0 || d2[n] < d2[best] ||
          (d2[n] == d2[best] && id[n] < id[best])) best = n;
    }
    used[best] = true;
    lg[t] = dp[best] * 0.08838834764831843 - sqrt(d2[best] + 1e-12);
  }
  double m = lg[0];
#pragma unroll
  for (int t = 1; t < TOPN; ++t) m = fmax(m, lg[t]);
  double sum = 0.0;
#pragma unroll
  for (int t = 0; t < TOPN; ++t) sum += exp(lg[t] - m);
  importance[q] = (float)(1.0 / sum);  // max softmax = 1/sum
}

// ---------------------------------------------------------------------------
// Kernel 7: softmax over Lq per batch, write reconstructed query (f64 internal).
__global__ __launch_bounds__(128) void out_kernel(const float* __restrict__ importance,
                                                  const int* __restrict__ qtok,
                                                  float* __restrict__ out) {
  const int b = blockIdx.x, i = threadIdx.x;  // 4 blocks x 128 threads
  __shared__ double sred[2];
  const double v = (double)importance[b * 128 + i];
  double m = v;
#pragma unroll
  for (int off = 32; off; off >>= 1) m = fmax(m, __shfl_xor(m, off, 64));
  if ((i & 63) == 0) sred[i >> 6] = m;
  __syncthreads();
  const double M = fmax(sred[0], sred[1]);
  const double e = exp(v - M);
  double s = e;
#pragma unroll
  for (int off = 32; off; off >>= 1) s += __shfl_xor(s, off, 64);
  __syncthreads();
  if ((i & 63) == 0) sred[i >> 6] = s;
  __syncthreads();
  const double S = sred[0] + sred[1];
  out[b * 128 + i] = (float)((double)qtok[b * 128 + i] * (e / S) * 128.0);
}

// ---------------------------------------------------------------------------
extern "C" void kernel_launch(void* const* d_in, const int* in_sizes, int n_in,
                              void* d_out, int out_size, void* d_ws, size_t ws_size,
                              hipStream_t stream) {
  const int* qtok = (const int*)d_in[0];
  const int* ctok = (const int*)d_in[1];
  const float* emb = (const float*)d_in[2];
  const float* W = (const float*)d_in[3];
  const float* bvec = (const float*)d_in[4];
  float* out = (float*)d_out;

  char* ws = (char*)d_ws;
  double* rd2 = (double*)ws;                       // 64 KB (8B-aligned first)
  double* rdp = rd2 + NQ * NCAND;                  // 64 KB
  float* cn2 = (float*)(rdp + NQ * NCAND);         // 256 KB
  float* qp = cn2 + LCTX;                          // 256 KB
  float* imp = qp + (size_t)NQ * D;                // 2 KB
  int* cand = (int*)(imp + NQ);                    // 32 KB
  float2* partials = (float2*)(cand + NQ * NCAND); // 2 MB

  cn2_kernel<<<LCTX / 8, 256, 0, stream>>>(ctok, emb, cn2);
  qprep_kernel<<<NQ, 128, 0, stream>>>(qtok, emb, W, bvec, qp);
  dist_topk_kernel<<<dim3(NCH, NQT), 512, 0, stream>>>(ctok, qtok, emb, cn2, partials);
  merge16_kernel<<<NQ / 64, 64, 0, stream>>>(partials, cand);
  refine_kernel<<<NQ * NCAND / 8, 256, 0, stream>>>(cand, qtok, ctok, emb, qp, rd2, rdp);
  final_kernel<<<NQ / 64, 64, 0, stream>>>(rd2, rdp, cand, imp);
  out_kernel<<<4, 128, 0, stream>>>(imp, qtok, out);
}

// Round 5
// 609.249 us; speedup vs baseline: 12.5011x; 12.2096x over previous
//
#include <hip/hip_runtime.h>
#include <math.h>

// Problem constants
#define D      128
#define NQ     512          // B * LQ = 4 * 128
#define LCTX   65536
#define TOPN   8
#define NCAND  16           // coarse candidates refined in f64
// Distance-kernel tiling
#define QT     64           // queries per block (4 waves x 16)
#define CCHUNK 1024         // contexts per block
#define CSTEP  128          // contexts staged per LDS step
#define NCH    (LCTX / CCHUNK)   // 64 chunks
#define NQT    (NQ / QT)         // 8 query tiles
#define FINF   3.0e38f

typedef __attribute__((ext_vector_type(8))) __bf16 bf16x8;
typedef __attribute__((ext_vector_type(4))) float f32x4;

// pack two f32 -> two bf16 (round-to-nearest-ish; coarse path only)
static __device__ __forceinline__ unsigned pack2(float a, float b) {
  const unsigned ua = (__float_as_uint(a) + 0x8000u) >> 16;
  const unsigned ub = (__float_as_uint(b) + 0x8000u) & 0xffff0000u;
  return ua | ub;
}

// ---------------------------------------------------------------------------
// Kernel 1: ||c||^2 for every context position (fp32, coarse rank-key input).
__global__ __launch_bounds__(256) void cn2_kernel(const int* __restrict__ ctok,
                                                  const float* __restrict__ emb,
                                                  float* __restrict__ cn2) {
  const int g = threadIdx.x >> 5, l = threadIdx.x & 31;
  const int row = blockIdx.x * 8 + g;
  const int tok = ctok[row];
  const float4 v = *(const float4*)(emb + (size_t)tok * D + 4 * l);
  float p = v.x * v.x + v.y * v.y + v.z * v.z + v.w * v.w;
#pragma unroll
  for (int off = 16; off; off >>= 1) p += __shfl_xor(p, off, 32);
  if (l == 0) cn2[row] = p;
}

// ---------------------------------------------------------------------------
// Kernel 2: qp = q @ W + b.  One block (128 thr) per query.  fp32.
__global__ __launch_bounds__(128) void qprep_kernel(const int* __restrict__ qtok,
                                                    const float* __restrict__ emb,
                                                    const float* __restrict__ W,
                                                    const float* __restrict__ bvec,
                                                    float* __restrict__ qp) {
  const int q = blockIdx.x;
  const int d = threadIdx.x;  // 0..127
  __shared__ float sq[D];
  const int tok = qtok[q];
  sq[d] = emb[(size_t)tok * D + d];
  __syncthreads();
  float acc = bvec[d];
  for (int k = 0; k < D; ++k) acc = fmaf(sq[k], W[k * D + d], acc);
  qp[(size_t)q * D + d] = acc;
}

// ---------------------------------------------------------------------------
// Kernel 3: coarse scores via bf16 MFMA + streaming top-8 per (query, chunk).
// Grid (NCH, NQT), 256 threads = 4 waves.  Wave w owns queries qbase+16w..+15,
// one query per lane-column (C/D col = lane&15) -> per-lane top-8 state is
// only 16 VGPRs (R3/R4 post-mortem: fp32 4q/2q-per-thread designs spilled
// their 64-reg selection state to scratch at 18.5 GB of HBM traffic).
// A = contexts (M), B = queries (N), D[ctx][query] = q.c accumulated fp32.
// LDS C-tile: bf16, 16B chunks XOR-swizzled: chunk c of row r at c^(r&7).
__global__ __launch_bounds__(256) void dist_topk_kernel(
    const int* __restrict__ ctok, const int* __restrict__ qtok,
    const float* __restrict__ emb, const float* __restrict__ cn2,
    float2* __restrict__ partials) {
  __shared__ __align__(16) unsigned short sCt[CSTEP * D];  // 32 KB bf16 tile
  __shared__ __align__(16) float scn2[CCHUNK];             // 4 KB

  const int tid = threadIdx.x;
  const int wid = tid >> 6, lane = tid & 63;
  const int n = lane & 15;         // query col within wave / A row m
  const int qq = lane >> 4;        // k-quad (0..3) and C/D row group
  const int chunk = blockIdx.x, qtile = blockIdx.y;
  const int qbase = qtile * QT, cbase0 = chunk * CCHUNK;

  // ---- stage cn2 for the whole chunk ----
#pragma unroll
  for (int i = 0; i < CCHUNK / 256; ++i) scn2[i * 256 + tid] = cn2[cbase0 + i * 256 + tid];

  // ---- B-fragments (queries), loaded once: B[n][k=32kk+8qq+j] ----
  bf16x8 bq[4];
  {
    const int tq = qtok[qbase + wid * 16 + n];
    const float* qrow = emb + (size_t)tq * D;
#pragma unroll
    for (int kk = 0; kk < 4; ++kk) {
      const float4 a = *(const float4*)(qrow + 32 * kk + 8 * qq);
      const float4 b = *(const float4*)(qrow + 32 * kk + 8 * qq + 4);
      uint4 pk;
      pk.x = pack2(a.x, a.y); pk.y = pack2(a.z, a.w);
      pk.z = pack2(b.x, b.y); pk.w = pack2(b.z, b.w);
      bq[kk] = __builtin_bit_cast(bf16x8, pk);
    }
  }

  // ---- per-lane top-8 (one query) ----
  float bs[8]; int bi[8]; float bmax = FINF;
#pragma unroll
  for (int t = 0; t < 8; ++t) { bs[t] = FINF; bi[t] = 0; }

  const int srow = tid >> 1, shalf = tid & 1;  // staging: 2 threads per ctx row

  for (int st = 0; st < CCHUNK / CSTEP; ++st) {
    const int cb = cbase0 + st * CSTEP;
    __syncthreads();
    // ---- stage 128 contexts as bf16 into LDS (f32 load -> pack -> b128) ----
    {
      const int tok = ctok[cb + srow];
      const float* crow = emb + (size_t)tok * D;
#pragma unroll
      for (int i = 0; i < 8; ++i) {
        const int c = 8 * shalf + i;  // 16B chunk = dims 8c..8c+7
        const float4 a = *(const float4*)(crow + 8 * c);
        const float4 b = *(const float4*)(crow + 8 * c + 4);
        uint4 pk;
        pk.x = pack2(a.x, a.y); pk.y = pack2(a.z, a.w);
        pk.z = pack2(b.x, b.y); pk.w = pack2(b.z, b.w);
        *(uint4*)(&sCt[(size_t)srow * D + 8 * (c ^ (srow & 7))]) = pk;
      }
    }
    __syncthreads();

    // ---- 8 tiles of 16 contexts: 4 MFMAs (K=128) + selection ----
#pragma unroll
    for (int tt = 0; tt < 8; ++tt) {
      f32x4 acc = {0.f, 0.f, 0.f, 0.f};
#pragma unroll
      for (int kk = 0; kk < 4; ++kk) {
        const int m = 16 * tt + n;  // context row in staged block
        const bf16x8 af = *(const bf16x8*)(&sCt[(size_t)m * D + 8 * ((4 * kk + qq) ^ (m & 7))]);
        acc = __builtin_amdgcn_mfma_f32_16x16x32_bf16(af, bq[kk], acc, 0, 0, 0);
      }
      // C/D: col=lane&15 (query), row = 4*qq + r (context within tile)
      const f32x4 cv = *(const f32x4*)(&scn2[st * CSTEP + 16 * tt + 4 * qq]);
#pragma unroll
      for (int r = 0; r < 4; ++r) {
        const float s = fmaf(-2.f, acc[r], cv[r]);
        if (s < bmax) {
          const int idx = cb + 16 * tt + 4 * qq + r;
          bool done = false;
#pragma unroll
          for (int t = 0; t < 8; ++t) {
            const bool hit = (!done) && (bs[t] == bmax);
            if (hit) { bs[t] = s; bi[t] = idx; done = true; }
          }
          float mx = bs[0];
#pragma unroll
          for (int t = 1; t < 8; ++t) mx = fmaxf(mx, bs[t]);
          bmax = mx;
        }
      }
    }
  }

  // ---- merge: 4 lanes (qq groups) x 8 slots -> top-8 per (query, chunk) ----
  __syncthreads();
  float2* mb = (float2*)sCt;  // 64 queries x 32 candidates = 16 KB, reuses tile
  const int qlocal = wid * 16 + n;
#pragma unroll
  for (int t = 0; t < 8; ++t)
    mb[qlocal * 32 + qq * 8 + t] = make_float2(bs[t], __int_as_float(bi[t]));
  __syncthreads();
  if (tid < QT) {
    float ts[8]; int ti8[8]; float tmax = FINF;
#pragma unroll
    for (int t = 0; t < 8; ++t) { ts[t] = FINF; ti8[t] = 0; }
    for (int c = 0; c < 32; ++c) {
      const float2 cd = mb[tid * 32 + c];
      if (cd.x < tmax) {
        bool done = false;
#pragma unroll
        for (int t = 0; t < 8; ++t) {
          const bool hit = (!done) && (ts[t] == tmax);
          if (hit) { ts[t] = cd.x; ti8[t] = __float_as_int(cd.y); done = true; }
        }
        float mx = ts[0];
#pragma unroll
        for (int t = 1; t < 8; ++t) mx = fmaxf(mx, ts[t]);
        tmax = mx;
      }
    }
    const int q = qbase + tid;
#pragma unroll
    for (int t = 0; t < 8; ++t)
      partials[(size_t)(chunk * 8 + t) * NQ + q] = make_float2(ts[t], __int_as_float(ti8[t]));
  }
}

// ---------------------------------------------------------------------------
// Kernel 4: per-query coarse merge of 512 candidates -> top-16 indices.
__global__ __launch_bounds__(64) void merge16_kernel(const float2* __restrict__ partials,
                                                     int* __restrict__ cand) {
  const int q = blockIdx.x * 64 + threadIdx.x;
  float ts[NCAND]; int ti[NCAND]; float tmax = FINF;
#pragma unroll
  for (int t = 0; t < NCAND; ++t) { ts[t] = FINF; ti[t] = 0; }
  for (int c = 0; c < NCH * 8; ++c) {
    const float2 cd = partials[(size_t)c * NQ + q];  // coalesced across lanes
    if (cd.x < tmax) {
      bool done = false;
#pragma unroll
      for (int t = 0; t < NCAND; ++t) {
        const bool hit = (!done) && (ts[t] == tmax);
        if (hit) { ts[t] = cd.x; ti[t] = __float_as_int(cd.y); done = true; }
      }
      float m = ts[0];
#pragma unroll
      for (int t = 1; t < NCAND; ++t) m = fmaxf(m, ts[t]);
      tmax = m;
    }
  }
#pragma unroll
  for (int t = 0; t < NCAND; ++t) cand[q * NCAND + t] = ti[t];
}

// ---------------------------------------------------------------------------
// Kernel 5: f64 refine — exact d^2 and dp = qp.c per (q, cand).
__global__ __launch_bounds__(256) void refine_kernel(const int* __restrict__ cand,
                                                     const int* __restrict__ qtok,
                                                     const int* __restrict__ ctok,
                                                     const float* __restrict__ emb,
                                                     const float* __restrict__ qp,
                                                     double* __restrict__ rd2,
                                                     double* __restrict__ rdp) {
  const int g = threadIdx.x >> 5, l = threadIdx.x & 31;
  const int p = blockIdx.x * 8 + g;          // 0 .. NQ*NCAND-1
  const int q = p >> 4, n = p & (NCAND - 1);
  const int idx = cand[q * NCAND + n];
  const int tc = ctok[idx], tq = qtok[q];
  const float4 c4 = *(const float4*)(emb + (size_t)tc * D + 4 * l);
  const float4 q4 = *(const float4*)(emb + (size_t)tq * D + 4 * l);
  const float4 p4 = *(const float4*)(qp + (size_t)q * D + 4 * l);
  const double dx = (double)q4.x - (double)c4.x, dy = (double)q4.y - (double)c4.y;
  const double dz = (double)q4.z - (double)c4.z, dw = (double)q4.w - (double)c4.w;
  double dd = dx * dx + dy * dy + dz * dz + dw * dw;
  double pp = (double)p4.x * (double)c4.x + (double)p4.y * (double)c4.y +
              (double)p4.z * (double)c4.z + (double)p4.w * (double)c4.w;
#pragma unroll
  for (int off = 16; off; off >>= 1) {
    dd += __shfl_xor(dd, off, 32);
    pp += __shfl_xor(pp, off, 32);
  }
  if (l == 0) { rd2[q * NCAND + n] = dd; rdp[q * NCAND + n] = pp; }
}

// ---------------------------------------------------------------------------
// Kernel 6: exact top-8 of 16 by f64 d^2, logits + softmax-max (f64).
__global__ __launch_bounds__(64) void final_kernel(const double* __restrict__ rd2,
                                                   const double* __restrict__ rdp,
                                                   const int* __restrict__ cand,
                                                   float* __restrict__ importance) {
  const int q = blockIdx.x * 64 + threadIdx.x;
  double d2[NCAND], dp[NCAND]; int id[NCAND]; bool used[NCAND];
#pragma unroll
  for (int n = 0; n < NCAND; ++n) {
    d2[n] = rd2[q * NCAND + n];
    dp[n] = rdp[q * NCAND + n];
    id[n] = cand[q * NCAND + n];
    used[n] = false;
  }
  double lg[TOPN];
  for (int t = 0; t < TOPN; ++t) {
    int best = -1;
    for (int n = 0; n < NCAND; ++n) {
      if (used[n]) continue;
      if (best < 0 || d2[n] < d2[best] ||
          (d2[n] == d2[best] && id[n] < id[best])) best = n;
    }
    used[best] = true;
    lg[t] = dp[best] * 0.08838834764831843 - sqrt(d2[best] + 1e-12);
  }
  double m = lg[0];
#pragma unroll
  for (int t = 1; t < TOPN; ++t) m = fmax(m, lg[t]);
  double sum = 0.0;
#pragma unroll
  for (int t = 0; t < TOPN; ++t) sum += exp(lg[t] - m);
  importance[q] = (float)(1.0 / sum);  // max softmax = 1/sum
}

// ---------------------------------------------------------------------------
// Kernel 7: softmax over Lq per batch, write reconstructed query (f64 internal).
__global__ __launch_bounds__(128) void out_kernel(const float* __restrict__ importance,
                                                  const int* __restrict__ qtok,
                                                  float* __restrict__ out) {
  const int b = blockIdx.x, i = threadIdx.x;  // 4 blocks x 128 threads
  __shared__ double sred[2];
  const double v = (double)importance[b * 128 + i];
  double m = v;
#pragma unroll
  for (int off = 32; off; off >>= 1) m = fmax(m, __shfl_xor(m, off, 64));
  if ((i & 63) == 0) sred[i >> 6] = m;
  __syncthreads();
  const double M = fmax(sred[0], sred[1]);
  const double e = exp(v - M);
  double s = e;
#pragma unroll
  for (int off = 32; off; off >>= 1) s += __shfl_xor(s, off, 64);
  __syncthreads();
  if ((i & 63) == 0) sred[i >> 6] = s;
  __syncthreads();
  const double S = sred[0] + sred[1];
  out[b * 128 + i] = (float)((double)qtok[b * 128 + i] * (e / S) * 128.0);
}

// ---------------------------------------------------------------------------
extern "C" void kernel_launch(void* const* d_in, const int* in_sizes, int n_in,
                              void* d_out, int out_size, void* d_ws, size_t ws_size,
                              hipStream_t stream) {
  const int* qtok = (const int*)d_in[0];
  const int* ctok = (const int*)d_in[1];
  const float* emb = (const float*)d_in[2];
  const float* W = (const float*)d_in[3];
  const float* bvec = (const float*)d_in[4];
  float* out = (float*)d_out;

  char* ws = (char*)d_ws;
  double* rd2 = (double*)ws;                       // 64 KB (8B-aligned first)
  double* rdp = rd2 + NQ * NCAND;                  // 64 KB
  float* cn2 = (float*)(rdp + NQ * NCAND);         // 256 KB
  float* qp = cn2 + LCTX;                          // 256 KB
  float* imp = qp + (size_t)NQ * D;                // 2 KB
  int* cand = (int*)(imp + NQ);                    // 32 KB
  float2* partials = (float2*)(cand + NQ * NCAND); // 2 MB

  cn2_kernel<<<LCTX / 8, 256, 0, stream>>>(ctok, emb, cn2);
  qprep_kernel<<<NQ, 128, 0, stream>>>(qtok, emb, W, bvec, qp);
  dist_topk_kernel<<<dim3(NCH, NQT), 256, 0, stream>>>(ctok, qtok, emb, cn2, partials);
  merge16_kernel<<<NQ / 64, 64, 0, stream>>>(partials, cand);
  refine_kernel<<<NQ * NCAND / 8, 256, 0, stream>>>(cand, qtok, ctok, emb, qp, rd2, rdp);
  final_kernel<<<NQ / 64, 64, 0, stream>>>(rd2, rdp, cand, imp);
  out_kernel<<<4, 128, 0, stream>>>(imp, qtok, out);
}

// Round 6
// 252.624 us; speedup vs baseline: 30.1487x; 2.4117x over previous
//
#include <hip/hip_runtime.h>
#include <math.h>

// Problem constants
#define D      128
#define NQ     512          // B * LQ = 4 * 128
#define LCTX   65536
#define TOPN   8
#define NCAND  16           // coarse candidates refined in f64
// Distance-kernel tiling
#define QT     64           // queries per block (4 waves x 16)
#define CCHUNK 1024         // contexts per block
#define CSTEP  128          // contexts staged per LDS step
#define NCH    (LCTX / CCHUNK)   // 64 chunks
#define NCANDTOT (NCH * 8)       // 512 coarse candidates per query
#define NQT    (NQ / QT)         // 8 query tiles
#define FINF   3.0e38f

typedef __attribute__((ext_vector_type(8))) __bf16 bf16x8;
typedef __attribute__((ext_vector_type(4))) float f32x4;

// pack two f32 -> two bf16 (round-to-nearest-ish; coarse path only)
static __device__ __forceinline__ unsigned pack2(float a, float b) {
  const unsigned ua = (__float_as_uint(a) + 0x8000u) >> 16;
  const unsigned ub = (__float_as_uint(b) + 0x8000u) & 0xffff0000u;
  return ua | ub;
}

// ---------------------------------------------------------------------------
// Kernel 1: ||c||^2 for every context position (fp32, coarse rank-key input).
__global__ __launch_bounds__(256) void cn2_kernel(const int* __restrict__ ctok,
                                                  const float* __restrict__ emb,
                                                  float* __restrict__ cn2) {
  const int g = threadIdx.x >> 5, l = threadIdx.x & 31;
  const int row = blockIdx.x * 8 + g;
  const int tok = ctok[row];
  const float4 v = *(const float4*)(emb + (size_t)tok * D + 4 * l);
  float p = v.x * v.x + v.y * v.y + v.z * v.z + v.w * v.w;
#pragma unroll
  for (int off = 16; off; off >>= 1) p += __shfl_xor(p, off, 32);
  if (l == 0) cn2[row] = p;
}

// ---------------------------------------------------------------------------
// Kernel 2: qp = q @ W + b.  One block (128 thr) per query.  fp32.
__global__ __launch_bounds__(128) void qprep_kernel(const int* __restrict__ qtok,
                                                    const float* __restrict__ emb,
                                                    const float* __restrict__ W,
                                                    const float* __restrict__ bvec,
                                                    float* __restrict__ qp) {
  const int q = blockIdx.x;
  const int d = threadIdx.x;  // 0..127
  __shared__ float sq[D];
  const int tok = qtok[q];
  sq[d] = emb[(size_t)tok * D + d];
  __syncthreads();
  float acc = bvec[d];
  for (int k = 0; k < D; ++k) acc = fmaf(sq[k], W[k * D + d], acc);
  qp[(size_t)q * D + d] = acc;
}

// ---------------------------------------------------------------------------
// Kernel 3: coarse scores via bf16 MFMA + streaming top-8 per (query, chunk).
// Grid (NCH, NQT), 256 threads = 4 waves.  Wave w owns queries qbase+16w..+15,
// one query per lane-column (C/D col = lane&15) -> per-lane top-8 state is
// only 16 VGPRs (R3/R4 post-mortem: fp32 multi-q-per-thread designs spilled
// their selection state to scratch at 18.5 GB of HBM traffic).
// A = contexts (M), B = queries (N), D[ctx][query] = q.c accumulated fp32.
// LDS C-tile: bf16, 16B chunks XOR-swizzled: chunk c of row r at c^(r&7).
__global__ __launch_bounds__(256) void dist_topk_kernel(
    const int* __restrict__ ctok, const int* __restrict__ qtok,
    const float* __restrict__ emb, const float* __restrict__ cn2,
    float2* __restrict__ partials) {
  __shared__ __align__(16) unsigned short sCt[CSTEP * D];  // 32 KB bf16 tile
  __shared__ __align__(16) float scn2[CCHUNK];             // 4 KB

  const int tid = threadIdx.x;
  const int wid = tid >> 6, lane = tid & 63;
  const int n = lane & 15;         // query col within wave / A row m
  const int qq = lane >> 4;        // k-quad (0..3) and C/D row group
  const int chunk = blockIdx.x, qtile = blockIdx.y;
  const int qbase = qtile * QT, cbase0 = chunk * CCHUNK;

  // ---- stage cn2 for the whole chunk ----
#pragma unroll
  for (int i = 0; i < CCHUNK / 256; ++i) scn2[i * 256 + tid] = cn2[cbase0 + i * 256 + tid];

  // ---- B-fragments (queries), loaded once: B[n][k=32kk+8qq+j] ----
  bf16x8 bq[4];
  {
    const int tq = qtok[qbase + wid * 16 + n];
    const float* qrow = emb + (size_t)tq * D;
#pragma unroll
    for (int kk = 0; kk < 4; ++kk) {
      const float4 a = *(const float4*)(qrow + 32 * kk + 8 * qq);
      const float4 b = *(const float4*)(qrow + 32 * kk + 8 * qq + 4);
      uint4 pk;
      pk.x = pack2(a.x, a.y); pk.y = pack2(a.z, a.w);
      pk.z = pack2(b.x, b.y); pk.w = pack2(b.z, b.w);
      bq[kk] = __builtin_bit_cast(bf16x8, pk);
    }
  }

  // ---- per-lane top-8 (one query) ----
  float bs[8]; int bi[8]; float bmax = FINF;
#pragma unroll
  for (int t = 0; t < 8; ++t) { bs[t] = FINF; bi[t] = 0; }

  const int srow = tid >> 1, shalf = tid & 1;  // staging: 2 threads per ctx row

  for (int st = 0; st < CCHUNK / CSTEP; ++st) {
    const int cb = cbase0 + st * CSTEP;
    __syncthreads();
    // ---- stage 128 contexts as bf16 into LDS (f32 load -> pack -> b128) ----
    {
      const int tok = ctok[cb + srow];
      const float* crow = emb + (size_t)tok * D;
#pragma unroll
      for (int i = 0; i < 8; ++i) {
        const int c = 8 * shalf + i;  // 16B chunk = dims 8c..8c+7
        const float4 a = *(const float4*)(crow + 8 * c);
        const float4 b = *(const float4*)(crow + 8 * c + 4);
        uint4 pk;
        pk.x = pack2(a.x, a.y); pk.y = pack2(a.z, a.w);
        pk.z = pack2(b.x, b.y); pk.w = pack2(b.z, b.w);
        *(uint4*)(&sCt[(size_t)srow * D + 8 * (c ^ (srow & 7))]) = pk;
      }
    }
    __syncthreads();

    // ---- 8 tiles of 16 contexts: 4 MFMAs (K=128) + selection ----
#pragma unroll
    for (int tt = 0; tt < 8; ++tt) {
      f32x4 acc = {0.f, 0.f, 0.f, 0.f};
#pragma unroll
      for (int kk = 0; kk < 4; ++kk) {
        const int m = 16 * tt + n;  // context row in staged block
        const bf16x8 af = *(const bf16x8*)(&sCt[(size_t)m * D + 8 * ((4 * kk + qq) ^ (m & 7))]);
        acc = __builtin_amdgcn_mfma_f32_16x16x32_bf16(af, bq[kk], acc, 0, 0, 0);
      }
      // C/D: col=lane&15 (query), row = 4*qq + r (context within tile)
      const f32x4 cv = *(const f32x4*)(&scn2[st * CSTEP + 16 * tt + 4 * qq]);
#pragma unroll
      for (int r = 0; r < 4; ++r) {
        const float s = fmaf(-2.f, acc[r], cv[r]);
        if (s < bmax) {
          const int idx = cb + 16 * tt + 4 * qq + r;
          bool done = false;
#pragma unroll
          for (int t = 0; t < 8; ++t) {
            const bool hit = (!done) && (bs[t] == bmax);
            if (hit) { bs[t] = s; bi[t] = idx; done = true; }
          }
          float mx = bs[0];
#pragma unroll
          for (int t = 1; t < 8; ++t) mx = fmaxf(mx, bs[t]);
          bmax = mx;
        }
      }
    }
  }

  // ---- merge: 4 lanes (qq groups) x 8 slots -> top-8 per (query, chunk) ----
  __syncthreads();
  float2* mb = (float2*)sCt;  // 64 queries x 32 candidates = 16 KB, reuses tile
  const int qlocal = wid * 16 + n;
#pragma unroll
  for (int t = 0; t < 8; ++t)
    mb[qlocal * 32 + qq * 8 + t] = make_float2(bs[t], __int_as_float(bi[t]));
  __syncthreads();
  if (tid < QT) {
    float ts[8]; int ti8[8]; float tmax = FINF;
#pragma unroll
    for (int t = 0; t < 8; ++t) { ts[t] = FINF; ti8[t] = 0; }
    for (int c = 0; c < 32; ++c) {
      const float2 cd = mb[tid * 32 + c];
      if (cd.x < tmax) {
        bool done = false;
#pragma unroll
        for (int t = 0; t < 8; ++t) {
          const bool hit = (!done) && (ts[t] == tmax);
          if (hit) { ts[t] = cd.x; ti8[t] = __float_as_int(cd.y); done = true; }
        }
        float mx = ts[0];
#pragma unroll
        for (int t = 1; t < 8; ++t) mx = fmaxf(mx, ts[t]);
        tmax = mx;
      }
    }
    const int q = qbase + tid;
    // [q][512] layout: wave-coalesced reads in merge16_kernel
#pragma unroll
    for (int t = 0; t < 8; ++t)
      partials[(size_t)q * NCANDTOT + chunk * 8 + t] =
          make_float2(ts[t], __int_as_float(ti8[t]));
  }
}

// ---------------------------------------------------------------------------
// Kernel 4: per-query merge of 512 candidates -> top-16, one WAVE per query.
// (R5 post-mortem: the 1-thread-per-query version was 375 us at 0.089%
// occupancy — latency-bound.)  Each lane holds 8 candidates; 16 rounds of
// local-min scan + wave argmin (shfl_xor, deterministic idx tie-break).
__global__ __launch_bounds__(256) void merge16_kernel(const float2* __restrict__ partials,
                                                      int* __restrict__ cand) {
  const int lane = threadIdx.x & 63;
  const int q = blockIdx.x * 4 + (threadIdx.x >> 6);  // 4 waves per block

  float v[8]; int vi[8];
  const float2* pq = partials + (size_t)q * NCANDTOT;
#pragma unroll
  for (int j = 0; j < 8; ++j) {
    const float2 cd = pq[64 * j + lane];  // coalesced 512B per wave-load
    v[j] = cd.x; vi[j] = __float_as_int(cd.y);
  }

  unsigned consumed = 0;
  int myc = 0;
#pragma unroll
  for (int t = 0; t < NCAND; ++t) {
    // local min over unconsumed slots (compile-time indices only)
    float lmin = FINF; int li = 0x7fffffff; int ls = 0;
#pragma unroll
    for (int j = 0; j < 8; ++j) {
      const bool take = !((consumed >> j) & 1u) && (v[j] < lmin);
      lmin = take ? v[j] : lmin;
      li = take ? vi[j] : li;
      ls = take ? j : ls;
    }
    // wave argmin; tie-break by candidate index (all indices distinct)
    float m = lmin; int pidx = li; int pwho = (lane << 3) | ls;
#pragma unroll
    for (int off = 32; off; off >>= 1) {
      const float om = __shfl_xor(m, off, 64);
      const int oi = __shfl_xor(pidx, off, 64);
      const int ow = __shfl_xor(pwho, off, 64);
      const bool better = (om < m) || (om == m && oi < pidx);
      m = better ? om : m; pidx = better ? oi : pidx; pwho = better ? ow : pwho;
    }
    if ((pwho >> 3) == lane) consumed |= 1u << (pwho & 7);
    if (lane == t) myc = pidx;
  }
  if (lane < NCAND) cand[q * NCAND + lane] = myc;
}

// ---------------------------------------------------------------------------
// Kernel 5: f64 refine — exact d^2 and dp = qp.c per (q, cand).
__global__ __launch_bounds__(256) void refine_kernel(const int* __restrict__ cand,
                                                     const int* __restrict__ qtok,
                                                     const int* __restrict__ ctok,
                                                     const float* __restrict__ emb,
                                                     const float* __restrict__ qp,
                                                     double* __restrict__ rd2,
                                                     double* __restrict__ rdp) {
  const int g = threadIdx.x >> 5, l = threadIdx.x & 31;
  const int p = blockIdx.x * 8 + g;          // 0 .. NQ*NCAND-1
  const int q = p >> 4, n = p & (NCAND - 1);
  const int idx = cand[q * NCAND + n];
  const int tc = ctok[idx], tq = qtok[q];
  const float4 c4 = *(const float4*)(emb + (size_t)tc * D + 4 * l);
  const float4 q4 = *(const float4*)(emb + (size_t)tq * D + 4 * l);
  const float4 p4 = *(const float4*)(qp + (size_t)q * D + 4 * l);
  const double dx = (double)q4.x - (double)c4.x, dy = (double)q4.y - (double)c4.y;
  const double dz = (double)q4.z - (double)c4.z, dw = (double)q4.w - (double)c4.w;
  double dd = dx * dx + dy * dy + dz * dz + dw * dw;
  double pp = (double)p4.x * (double)c4.x + (double)p4.y * (double)c4.y +
              (double)p4.z * (double)c4.z + (double)p4.w * (double)c4.w;
#pragma unroll
  for (int off = 16; off; off >>= 1) {
    dd += __shfl_xor(dd, off, 32);
    pp += __shfl_xor(pp, off, 32);
  }
  if (l == 0) { rd2[q * NCAND + n] = dd; rdp[q * NCAND + n] = pp; }
}

// ---------------------------------------------------------------------------
// Kernel 6: exact top-8 of 16 by f64 d^2, logits + softmax-max (f64).
__global__ __launch_bounds__(64) void final_kernel(const double* __restrict__ rd2,
                                                   const double* __restrict__ rdp,
                                                   const int* __restrict__ cand,
                                                   float* __restrict__ importance) {
  const int q = blockIdx.x * 64 + threadIdx.x;
  double d2[NCAND], dp[NCAND]; int id[NCAND]; bool used[NCAND];
#pragma unroll
  for (int n = 0; n < NCAND; ++n) {
    d2[n] = rd2[q * NCAND + n];
    dp[n] = rdp[q * NCAND + n];
    id[n] = cand[q * NCAND + n];
    used[n] = false;
  }
  double lg[TOPN];
  for (int t = 0; t < TOPN; ++t) {
    int best = -1;
    for (int n = 0; n < NCAND; ++n) {
      if (used[n]) continue;
      if (best < 0 || d2[n] < d2[best] ||
          (d2[n] == d2[best] && id[n] < id[best])) best = n;
    }
    used[best] = true;
    lg[t] = dp[best] * 0.08838834764831843 - sqrt(d2[best] + 1e-12);
  }
  double m = lg[0];
#pragma unroll
  for (int t = 1; t < TOPN; ++t) m = fmax(m, lg[t]);
  double sum = 0.0;
#pragma unroll
  for (int t = 0; t < TOPN; ++t) sum += exp(lg[t] - m);
  importance[q] = (float)(1.0 / sum);  // max softmax = 1/sum
}

// ---------------------------------------------------------------------------
// Kernel 7: softmax over Lq per batch, write reconstructed query (f64 internal).
__global__ __launch_bounds__(128) void out_kernel(const float* __restrict__ importance,
                                                  const int* __restrict__ qtok,
                                                  float* __restrict__ out) {
  const int b = blockIdx.x, i = threadIdx.x;  // 4 blocks x 128 threads
  __shared__ double sred[2];
  const double v = (double)importance[b * 128 + i];
  double m = v;
#pragma unroll
  for (int off = 32; off; off >>= 1) m = fmax(m, __shfl_xor(m, off, 64));
  if ((i & 63) == 0) sred[i >> 6] = m;
  __syncthreads();
  const double M = fmax(sred[0], sred[1]);
  const double e = exp(v - M);
  double s = e;
#pragma unroll
  for (int off = 32; off; off >>= 1) s += __shfl_xor(s, off, 64);
  __syncthreads();
  if ((i & 63) == 0) sred[i >> 6] = s;
  __syncthreads();
  const double S = sred[0] + sred[1];
  out[b * 128 + i] = (float)((double)qtok[b * 128 + i] * (e / S) * 128.0);
}

// ---------------------------------------------------------------------------
extern "C" void kernel_launch(void* const* d_in, const int* in_sizes, int n_in,
                              void* d_out, int out_size, void* d_ws, size_t ws_size,
                              hipStream_t stream) {
  const int* qtok = (const int*)d_in[0];
  const int* ctok = (const int*)d_in[1];
  const float* emb = (const float*)d_in[2];
  const float* W = (const float*)d_in[3];
  const float* bvec = (const float*)d_in[4];
  float* out = (float*)d_out;

  char* ws = (char*)d_ws;
  double* rd2 = (double*)ws;                       // 64 KB (8B-aligned first)
  double* rdp = rd2 + NQ * NCAND;                  // 64 KB
  float* cn2 = (float*)(rdp + NQ * NCAND);         // 256 KB
  float* qp = cn2 + LCTX;                          // 256 KB
  float* imp = qp + (size_t)NQ * D;                // 2 KB
  int* cand = (int*)(imp + NQ);                    // 32 KB
  float2* partials = (float2*)(cand + NQ * NCAND); // 2 MB

  cn2_kernel<<<LCTX / 8, 256, 0, stream>>>(ctok, emb, cn2);
  qprep_kernel<<<NQ, 128, 0, stream>>>(qtok, emb, W, bvec, qp);
  dist_topk_kernel<<<dim3(NCH, NQT), 256, 0, stream>>>(ctok, qtok, emb, cn2, partials);
  merge16_kernel<<<NQ / 4, 256, 0, stream>>>(partials, cand);
  refine_kernel<<<NQ * NCAND / 8, 256, 0, stream>>>(cand, qtok, ctok, emb, qp, rd2, rdp);
  final_kernel<<<NQ / 64, 64, 0, stream>>>(rd2, rdp, cand, imp);
  out_kernel<<<4, 128, 0, stream>>>(imp, qtok, out);
}

// Round 7
// 232.037 us; speedup vs baseline: 32.8237x; 1.0887x over previous
//
#include <hip/hip_runtime.h>
#include <math.h>

// Problem constants
#define D      128
#define NQ     512          // B * LQ = 4 * 128
#define LCTX   65536
#define TOPN   8
#define NCAND  16           // coarse candidates refined in f64
// Distance-kernel tiling
#define QT     64           // queries per block (4 waves x 16 per group)
#define CCHUNK 1024         // contexts per block (split across 2 wave-groups)
#define CSTEP  128          // contexts staged per LDS step per group
#define SRW    136          // padded LDS row stride in shorts (272 B != 0 mod 128B)
#define NCH    (LCTX / CCHUNK)   // 64 chunks
#define NCANDTOT (NCH * 8)       // 512 coarse candidates per query
#define NQT    (NQ / QT)         // 8 query tiles
#define FINF   3.0e38f

typedef __attribute__((ext_vector_type(8))) __bf16 bf16x8;
typedef __attribute__((ext_vector_type(4))) float f32x4;

// pack two f32 -> two bf16 (round-to-nearest-ish; coarse path only)
static __device__ __forceinline__ unsigned pack2(float a, float b) {
  const unsigned ua = (__float_as_uint(a) + 0x8000u) >> 16;
  const unsigned ub = (__float_as_uint(b) + 0x8000u) & 0xffff0000u;
  return ua | ub;
}

// ---------------------------------------------------------------------------
// Kernel 1: ||c||^2 for every context position (fp32, coarse rank-key input).
__global__ __launch_bounds__(256) void cn2_kernel(const int* __restrict__ ctok,
                                                  const float* __restrict__ emb,
                                                  float* __restrict__ cn2) {
  const int g = threadIdx.x >> 5, l = threadIdx.x & 31;
  const int row = blockIdx.x * 8 + g;
  const int tok = ctok[row];
  const float4 v = *(const float4*)(emb + (size_t)tok * D + 4 * l);
  float p = v.x * v.x + v.y * v.y + v.z * v.z + v.w * v.w;
#pragma unroll
  for (int off = 16; off; off >>= 1) p += __shfl_xor(p, off, 32);
  if (l == 0) cn2[row] = p;
}

// ---------------------------------------------------------------------------
// Kernel 2: qp = q @ W + b.  One block (128 thr) per query.  fp32.
__global__ __launch_bounds__(128) void qprep_kernel(const int* __restrict__ qtok,
                                                    const float* __restrict__ emb,
                                                    const float* __restrict__ W,
                                                    const float* __restrict__ bvec,
                                                    float* __restrict__ qp) {
  const int q = blockIdx.x;
  const int d = threadIdx.x;  // 0..127
  __shared__ float sq[D];
  const int tok = qtok[q];
  sq[d] = emb[(size_t)tok * D + d];
  __syncthreads();
  float acc = bvec[d];
  for (int k = 0; k < D; ++k) acc = fmaf(sq[k], W[k * D + d], acc);
  qp[(size_t)q * D + d] = acc;
}

// ---------------------------------------------------------------------------
// Kernel 3: coarse scores via bf16 MFMA + streaming top-8 per (query, chunk).
// Grid (NCH, NQT), 512 threads = 8 waves in TWO independent 4-wave groups;
// group g owns contexts [cbase + 512g, +512) with its own LDS tile -> two
// barrier domains per CU + 4 waves/SIMD (R6 post-mortem: 2 blocks/CU of
// 4 waves with a shared barrier was latency-bound at 25% VALU / 20% occ).
// LDS rows padded to 272 B: b128 reads are bank-conflict-free per lane-octet
// (R6: 256B stride row-aliasing cost 4.6e6 conflict cycles).
__global__ __launch_bounds__(512, 4) void dist_topk_kernel(
    const int* __restrict__ ctok, const int* __restrict__ qtok,
    const float* __restrict__ emb, const float* __restrict__ cn2,
    float2* __restrict__ partials) {
  __shared__ __align__(16) unsigned short sCt[2][CSTEP * SRW];  // 2 x 34816 B
  __shared__ __align__(16) float scn2[CCHUNK];                  // 4 KB

  const int tid = threadIdx.x;
  const int wid = tid >> 6, lane = tid & 63;
  const int g2 = wid >> 2, wg = wid & 3;   // group, wave-in-group
  const int n = lane & 15, qq = lane >> 4; // query col, k-quad / C-row group
  const int chunk = blockIdx.x, qtile = blockIdx.y;
  const int qbase = qtile * QT, cbase0 = chunk * CCHUNK;
  const int gbase = cbase0 + g2 * (CCHUNK / 2);

  scn2[tid] = cn2[cbase0 + tid];
  scn2[tid + 512] = cn2[cbase0 + tid + 512];

  // ---- B-fragments (queries), loaded once: B[n][k=32kk+8qq+j] ----
  bf16x8 bq[4];
  {
    const int tq = qtok[qbase + wg * 16 + n];
    const float* qrow = emb + (size_t)tq * D;
#pragma unroll
    for (int kk = 0; kk < 4; ++kk) {
      const float4 a = *(const float4*)(qrow + 32 * kk + 8 * qq);
      const float4 b = *(const float4*)(qrow + 32 * kk + 8 * qq + 4);
      uint4 pk;
      pk.x = pack2(a.x, a.y); pk.y = pack2(a.z, a.w);
      pk.z = pack2(b.x, b.y); pk.w = pack2(b.z, b.w);
      bq[kk] = __builtin_bit_cast(bf16x8, pk);
    }
  }

  // ---- per-lane top-8 (one query) ----
  float bs[8]; int bi[8]; float bmax = FINF;
#pragma unroll
  for (int t = 0; t < 8; ++t) { bs[t] = FINF; bi[t] = 0; }

#define INSERT(V, I) do { \
    bool done_ = false; \
    _Pragma("unroll") \
    for (int t_ = 0; t_ < 8; ++t_) { \
      const bool hit_ = (!done_) && (bs[t_] == bmax); \
      if (hit_) { bs[t_] = (V); bi[t_] = (I); done_ = true; } \
    } \
    float mx_ = bs[0]; \
    _Pragma("unroll") \
    for (int t_ = 1; t_ < 8; ++t_) mx_ = fmaxf(mx_, bs[t_]); \
    bmax = mx_; \
  } while (0)

  unsigned short* tile = sCt[g2];
  const int srow = (tid & 255) >> 1, shalf = tid & 1;  // 256 thr stage 128 rows

  for (int st = 0; st < CCHUNK / 2 / CSTEP; ++st) {
    const int cb = gbase + st * CSTEP;
    __syncthreads();
    // ---- stage 128 contexts as bf16 (f32 gather -> pack -> b128 write) ----
    {
      const int tok = ctok[cb + srow];
      const float* crow = emb + (size_t)tok * D;
#pragma unroll
      for (int i = 0; i < 8; ++i) {
        const int c = 8 * shalf + i;  // 16B chunk = dims 8c..8c+7
        const float4 a = *(const float4*)(crow + 8 * c);
        const float4 b = *(const float4*)(crow + 8 * c + 4);
        uint4 pk;
        pk.x = pack2(a.x, a.y); pk.y = pack2(a.z, a.w);
        pk.z = pack2(b.x, b.y); pk.w = pack2(b.z, b.w);
        *(uint4*)(&tile[srow * SRW + 8 * c]) = pk;
      }
    }
    __syncthreads();

    // ---- 8 tiles of 16 contexts: 4 MFMAs (K=128) + selection ----
#pragma unroll
    for (int tt = 0; tt < 8; ++tt) {
      f32x4 acc = {0.f, 0.f, 0.f, 0.f};
      const int m = 16 * tt + n;  // context row in staged block
#pragma unroll
      for (int kk = 0; kk < 4; ++kk) {
        const bf16x8 af = *(const bf16x8*)(&tile[m * SRW + 8 * (4 * kk + qq)]);
        acc = __builtin_amdgcn_mfma_f32_16x16x32_bf16(af, bq[kk], acc, 0, 0, 0);
      }
      // C/D: col=lane&15 (query), row = 4*qq + r (context within tile)
      const f32x4 cv = *(const f32x4*)(&scn2[g2 * 512 + st * CSTEP + 16 * tt + 4 * qq]);
      const int ibase = cb + 16 * tt + 4 * qq;
      const float s0 = fmaf(-2.f, acc[0], cv[0]);
      const float s1 = fmaf(-2.f, acc[1], cv[1]);
      const float s2 = fmaf(-2.f, acc[2], cv[2]);
      const float s3 = fmaf(-2.f, acc[3], cv[3]);
      // lane-local min first: one insert body on the common path
      const float mab = fminf(s0, s1); const int iab = (s1 < s0) ? ibase + 1 : ibase;
      const float mcd = fminf(s2, s3); const int icd = (s3 < s2) ? ibase + 3 : ibase + 2;
      const float mv = fminf(mab, mcd); const int mi = (mcd < mab) ? icd : iab;
      if (mv < bmax) INSERT(mv, mi);
      if (s0 < bmax && ibase + 0 != mi) INSERT(s0, ibase + 0);
      if (s1 < bmax && ibase + 1 != mi) INSERT(s1, ibase + 1);
      if (s2 < bmax && ibase + 2 != mi) INSERT(s2, ibase + 2);
      if (s3 < bmax && ibase + 3 != mi) INSERT(s3, ibase + 3);
    }
  }

  // ---- block merge: 8 qq-lanes x 8 slots x 2 groups -> 64 cands/query ----
  __syncthreads();
  float2* mb = (float2*)sCt;  // 64 queries x 65 (padded) float2 = 33280 B
  const int qlocal = wg * 16 + n;
#pragma unroll
  for (int t = 0; t < 8; ++t)
    mb[qlocal * 65 + g2 * 32 + qq * 8 + t] = make_float2(bs[t], __int_as_float(bi[t]));
  __syncthreads();

  // ---- octet-parallel top-8 of 64: wave wid -> queries wid*8..+7 ----
  const int octet = lane >> 3, ol = lane & 7;
  const int qrow2 = wid * 8 + octet;
  float v8[8]; int vi8[8];
#pragma unroll
  for (int j = 0; j < 8; ++j) {
    const float2 cd = mb[qrow2 * 65 + ol * 8 + j];
    v8[j] = cd.x; vi8[j] = __float_as_int(cd.y);
  }
  unsigned cons = 0; float rv = FINF; int ri = 0;
#pragma unroll
  for (int t = 0; t < TOPN; ++t) {
    float lmin = FINF; int li = 0x7fffffff; int ls = 0;
#pragma unroll
    for (int j = 0; j < 8; ++j) {
      const bool take = !((cons >> j) & 1u) && (v8[j] < lmin);
      lmin = take ? v8[j] : lmin;
      li = take ? vi8[j] : li;
      ls = take ? j : ls;
    }
    // octet argmin (xor 1,2,4 stay within the octet); idx tie-break
    float m = lmin; int pidx = li; int pwho = (ol << 3) | ls;
#pragma unroll
    for (int off = 1; off <= 4; off <<= 1) {
      const float om = __shfl_xor(m, off, 64);
      const int oi = __shfl_xor(pidx, off, 64);
      const int ow = __shfl_xor(pwho, off, 64);
      const bool better = (om < m) || (om == m && oi < pidx);
      m = better ? om : m; pidx = better ? oi : pidx; pwho = better ? ow : pwho;
    }
    if ((pwho >> 3) == ol) cons |= 1u << (pwho & 7);
    if (ol == t) { rv = m; ri = pidx; }
  }
  const int q = qbase + qrow2;
  partials[(size_t)q * NCANDTOT + chunk * 8 + ol] = make_float2(rv, __int_as_float(ri));
#undef INSERT
}

// ---------------------------------------------------------------------------
// Kernel 4: per-query merge of 512 candidates -> top-16, one WAVE per query.
__global__ __launch_bounds__(256) void merge16_kernel(const float2* __restrict__ partials,
                                                      int* __restrict__ cand) {
  const int lane = threadIdx.x & 63;
  const int q = blockIdx.x * 4 + (threadIdx.x >> 6);  // 4 waves per block

  float v[8]; int vi[8];
  const float2* pq = partials + (size_t)q * NCANDTOT;
#pragma unroll
  for (int j = 0; j < 8; ++j) {
    const float2 cd = pq[64 * j + lane];  // coalesced 512B per wave-load
    v[j] = cd.x; vi[j] = __float_as_int(cd.y);
  }

  unsigned consumed = 0;
  int myc = 0;
#pragma unroll
  for (int t = 0; t < NCAND; ++t) {
    float lmin = FINF; int li = 0x7fffffff; int ls = 0;
#pragma unroll
    for (int j = 0; j < 8; ++j) {
      const bool take = !((consumed >> j) & 1u) && (v[j] < lmin);
      lmin = take ? v[j] : lmin;
      li = take ? vi[j] : li;
      ls = take ? j : ls;
    }
    float m = lmin; int pidx = li; int pwho = (lane << 3) | ls;
#pragma unroll
    for (int off = 32; off; off >>= 1) {
      const float om = __shfl_xor(m, off, 64);
      const int oi = __shfl_xor(pidx, off, 64);
      const int ow = __shfl_xor(pwho, off, 64);
      const bool better = (om < m) || (om == m && oi < pidx);
      m = better ? om : m; pidx = better ? oi : pidx; pwho = better ? ow : pwho;
    }
    if ((pwho >> 3) == lane) consumed |= 1u << (pwho & 7);
    if (lane == t) myc = pidx;
  }
  if (lane < NCAND) cand[q * NCAND + lane] = myc;
}

// ---------------------------------------------------------------------------
// Kernel 5: f64 refine — exact d^2 and dp = qp.c per (q, cand).
__global__ __launch_bounds__(256) void refine_kernel(const int* __restrict__ cand,
                                                     const int* __restrict__ qtok,
                                                     const int* __restrict__ ctok,
                                                     const float* __restrict__ emb,
                                                     const float* __restrict__ qp,
                                                     double* __restrict__ rd2,
                                                     double* __restrict__ rdp) {
  const int g = threadIdx.x >> 5, l = threadIdx.x & 31;
  const int p = blockIdx.x * 8 + g;          // 0 .. NQ*NCAND-1
  const int q = p >> 4, n = p & (NCAND - 1);
  const int idx = cand[q * NCAND + n];
  const int tc = ctok[idx], tq = qtok[q];
  const float4 c4 = *(const float4*)(emb + (size_t)tc * D + 4 * l);
  const float4 q4 = *(const float4*)(emb + (size_t)tq * D + 4 * l);
  const float4 p4 = *(const float4*)(qp + (size_t)q * D + 4 * l);
  const double dx = (double)q4.x - (double)c4.x, dy = (double)q4.y - (double)c4.y;
  const double dz = (double)q4.z - (double)c4.z, dw = (double)q4.w - (double)c4.w;
  double dd = dx * dx + dy * dy + dz * dz + dw * dw;
  double pp = (double)p4.x * (double)c4.x + (double)p4.y * (double)c4.y +
              (double)p4.z * (double)c4.z + (double)p4.w * (double)c4.w;
#pragma unroll
  for (int off = 16; off; off >>= 1) {
    dd += __shfl_xor(dd, off, 32);
    pp += __shfl_xor(pp, off, 32);
  }
  if (l == 0) { rd2[q * NCAND + n] = dd; rdp[q * NCAND + n] = pp; }
}

// ---------------------------------------------------------------------------
// Kernel 6: exact top-8 of 16 by f64 d^2, logits + softmax-max (f64).
__global__ __launch_bounds__(64) void final_kernel(const double* __restrict__ rd2,
                                                   const double* __restrict__ rdp,
                                                   const int* __restrict__ cand,
                                                   float* __restrict__ importance) {
  const int q = blockIdx.x * 64 + threadIdx.x;
  double d2[NCAND], dp[NCAND]; int id[NCAND]; bool used[NCAND];
#pragma unroll
  for (int n = 0; n < NCAND; ++n) {
    d2[n] = rd2[q * NCAND + n];
    dp[n] = rdp[q * NCAND + n];
    id[n] = cand[q * NCAND + n];
    used[n] = false;
  }
  double lg[TOPN];
  for (int t = 0; t < TOPN; ++t) {
    int best = -1;
    for (int n = 0; n < NCAND; ++n) {
      if (used[n]) continue;
      if (best < 0 || d2[n] < d2[best] ||
          (d2[n] == d2[best] && id[n] < id[best])) best = n;
    }
    used[best] = true;
    lg[t] = dp[best] * 0.08838834764831843 - sqrt(d2[best] + 1e-12);
  }
  double m = lg[0];
#pragma unroll
  for (int t = 1; t < TOPN; ++t) m = fmax(m, lg[t]);
  double sum = 0.0;
#pragma unroll
  for (int t = 0; t < TOPN; ++t) sum += exp(lg[t] - m);
  importance[q] = (float)(1.0 / sum);  // max softmax = 1/sum
}

// ---------------------------------------------------------------------------
// Kernel 7: softmax over Lq per batch, write reconstructed query (f64 internal).
__global__ __launch_bounds__(128) void out_kernel(const float* __restrict__ importance,
                                                  const int* __restrict__ qtok,
                                                  float* __restrict__ out) {
  const int b = blockIdx.x, i = threadIdx.x;  // 4 blocks x 128 threads
  __shared__ double sred[2];
  const double v = (double)importance[b * 128 + i];
  double m = v;
#pragma unroll
  for (int off = 32; off; off >>= 1) m = fmax(m, __shfl_xor(m, off, 64));
  if ((i & 63) == 0) sred[i >> 6] = m;
  __syncthreads();
  const double M = fmax(sred[0], sred[1]);
  const double e = exp(v - M);
  double s = e;
#pragma unroll
  for (int off = 32; off; off >>= 1) s += __shfl_xor(s, off, 64);
  __syncthreads();
  if ((i & 63) == 0) sred[i >> 6] = s;
  __syncthreads();
  const double S = sred[0] + sred[1];
  out[b * 128 + i] = (float)((double)qtok[b * 128 + i] * (e / S) * 128.0);
}

// ---------------------------------------------------------------------------
extern "C" void kernel_launch(void* const* d_in, const int* in_sizes, int n_in,
                              void* d_out, int out_size, void* d_ws, size_t ws_size,
                              hipStream_t stream) {
  const int* qtok = (const int*)d_in[0];
  const int* ctok = (const int*)d_in[1];
  const float* emb = (const float*)d_in[2];
  const float* W = (const float*)d_in[3];
  const float* bvec = (const float*)d_in[4];
  float* out = (float*)d_out;

  char* ws = (char*)d_ws;
  double* rd2 = (double*)ws;                       // 64 KB (8B-aligned first)
  double* rdp = rd2 + NQ * NCAND;                  // 64 KB
  float* cn2 = (float*)(rdp + NQ * NCAND);         // 256 KB
  float* qp = cn2 + LCTX;                          // 256 KB
  float* imp = qp + (size_t)NQ * D;                // 2 KB
  int* cand = (int*)(imp + NQ);                    // 32 KB
  float2* partials = (float2*)(cand + NQ * NCAND); // 2 MB

  cn2_kernel<<<LCTX / 8, 256, 0, stream>>>(ctok, emb, cn2);
  qprep_kernel<<<NQ, 128, 0, stream>>>(qtok, emb, W, bvec, qp);
  dist_topk_kernel<<<dim3(NCH, NQT), 512, 0, stream>>>(ctok, qtok, emb, cn2, partials);
  merge16_kernel<<<NQ / 4, 256, 0, stream>>>(partials, cand);
  refine_kernel<<<NQ * NCAND / 8, 256, 0, stream>>>(cand, qtok, ctok, emb, qp, rd2, rdp);
  final_kernel<<<NQ / 64, 64, 0, stream>>>(rd2, rdp, cand, imp);
  out_kernel<<<4, 128, 0, stream>>>(imp, qtok, out);
}

// Round 8
// 215.475 us; speedup vs baseline: 35.3465x; 1.0769x over previous
//
#include <hip/hip_runtime.h>
#include <math.h>

// Problem constants
#define D      128
#define NQ     512          // B * LQ = 4 * 128
#define LCTX   65536
#define TOPN   8
#define NCAND  16           // coarse candidates refined in f64
// Distance-kernel tiling
#define QT     128          // queries per block (8 waves x 16) — NQT=4 halves staging redundancy
#define CCHUNK 512          // contexts per block
#define CSTEP  128          // contexts staged per LDS step
#define SRW    136          // padded LDS row stride in shorts (272 B)
#define NCH    (LCTX / CCHUNK)   // 128 chunks
#define NCANDTOT (NCH * 8)       // 1024 coarse candidates per query
#define NQT    (NQ / QT)         // 4 query tiles
#define FINF   3.0e38f

typedef __attribute__((ext_vector_type(8))) __bf16 bf16x8;
typedef __attribute__((ext_vector_type(4))) float f32x4;

// pack two f32 -> two bf16 (round-to-nearest-ish; coarse path only)
static __device__ __forceinline__ unsigned pack2(float a, float b) {
  const unsigned ua = (__float_as_uint(a) + 0x8000u) >> 16;
  const unsigned ub = (__float_as_uint(b) + 0x8000u) & 0xffff0000u;
  return ua | ub;
}

// ---------------------------------------------------------------------------
// Kernel 1: ||c||^2 for every context position (fp32, coarse rank-key input).
__global__ __launch_bounds__(256) void cn2_kernel(const int* __restrict__ ctok,
                                                  const float* __restrict__ emb,
                                                  float* __restrict__ cn2) {
  const int g = threadIdx.x >> 5, l = threadIdx.x & 31;
  const int row = blockIdx.x * 8 + g;
  const int tok = ctok[row];
  const float4 v = *(const float4*)(emb + (size_t)tok * D + 4 * l);
  float p = v.x * v.x + v.y * v.y + v.z * v.z + v.w * v.w;
#pragma unroll
  for (int off = 16; off; off >>= 1) p += __shfl_xor(p, off, 32);
  if (l == 0) cn2[row] = p;
}

// ---------------------------------------------------------------------------
// Kernel 2: qp = q @ W + b.  One block (128 thr) per query.  fp32.
__global__ __launch_bounds__(128) void qprep_kernel(const int* __restrict__ qtok,
                                                    const float* __restrict__ emb,
                                                    const float* __restrict__ W,
                                                    const float* __restrict__ bvec,
                                                    float* __restrict__ qp) {
  const int q = blockIdx.x;
  const int d = threadIdx.x;  // 0..127
  __shared__ float sq[D];
  const int tok = qtok[q];
  sq[d] = emb[(size_t)tok * D + d];
  __syncthreads();
  float acc = bvec[d];
  for (int k = 0; k < D; ++k) acc = fmaf(sq[k], W[k * D + d], acc);
  qp[(size_t)q * D + d] = acc;
}

// ---------------------------------------------------------------------------
// Kernel 3: coarse scores via bf16 MFMA + streaming top-8 per (query, chunk).
// Grid (NCH, NQT), 512 threads = 8 waves; wave w owns queries qbase+16w..+15,
// one query per lane-column -> per-lane top-8 state is 16 VGPRs.
// R7 post-mortem: staging was gather-DIVERGENCE bound (each load inst touched
// ~64 cache lines; ~16K scattered lane-requests/CU ~= the whole 111 us).
// Fix: one 32-lane group reads ONE emb row per instruction (512 B contiguous,
// 8 lines), for both C-tiles and the Q-tile; QT=128 halves the redundancy.
__global__ __launch_bounds__(512, 4) void dist_topk_kernel(
    const int* __restrict__ ctok, const int* __restrict__ qtok,
    const float* __restrict__ emb, const float* __restrict__ cn2,
    float2* __restrict__ partials) {
  __shared__ __align__(16) unsigned short sCt[CSTEP * SRW];  // 34816 B
  __shared__ __align__(16) float scn2[CCHUNK];               // 2 KB

  const int tid = threadIdx.x;
  const int wid = tid >> 6, lane = tid & 63;
  const int n = lane & 15, qq = lane >> 4;   // query col, k-quad / C-row group
  const int grp = tid >> 5, l = tid & 31;    // staging: 16 groups of 32 lanes
  const int chunk = blockIdx.x, qtile = blockIdx.y;
  const int qbase = qtile * QT, cbase0 = chunk * CCHUNK;

  scn2[tid] = cn2[cbase0 + tid];

  // ---- stage Q tile (once) into sCt: coalesced per-row reads, bf16 pack ----
#pragma unroll
  for (int i = 0; i < 4; ++i) {
    const int row = i * 32 + grp;  // wait: 128 rows by 16 groups -> 8 each
  }
  // (8 rows per 32-lane group)
  {
    int qtoks[8];
#pragma unroll
    for (int i = 0; i < 8; ++i) qtoks[i] = qtok[qbase + i * 16 + grp];
#pragma unroll
    for (int i = 0; i < 8; ++i) {
      const int row = i * 16 + grp;
      const float4 v = *(const float4*)(emb + (size_t)qtoks[i] * D + 4 * l);
      uint2 pk = make_uint2(pack2(v.x, v.y), pack2(v.z, v.w));
      *(uint2*)(&sCt[row * SRW + 4 * l]) = pk;  // dims 4l..4l+3
    }
  }
  __syncthreads();

  // ---- B-fragments from packed LDS: B[n][k=32kk+8qq+j] ----
  bf16x8 bq[4];
  {
    const int qr = 16 * wid + n;
#pragma unroll
    for (int kk = 0; kk < 4; ++kk)
      bq[kk] = *(const bf16x8*)(&sCt[qr * SRW + 8 * (4 * kk + qq)]);
  }

  // ---- per-lane top-8 (one query) ----
  float bs[8]; int bi[8]; float bmax = FINF;
#pragma unroll
  for (int t = 0; t < 8; ++t) { bs[t] = FINF; bi[t] = 0; }

#define INSERT(V, I) do { \
    bool done_ = false; \
    _Pragma("unroll") \
    for (int t_ = 0; t_ < 8; ++t_) { \
      const bool hit_ = (!done_) && (bs[t_] == bmax); \
      if (hit_) { bs[t_] = (V); bi[t_] = (I); done_ = true; } \
    } \
    float mx_ = bs[0]; \
    _Pragma("unroll") \
    for (int t_ = 1; t_ < 8; ++t_) mx_ = fmaxf(mx_, bs[t_]); \
    bmax = mx_; \
  } while (0)

  for (int st = 0; st < CCHUNK / CSTEP; ++st) {
    const int cb = cbase0 + st * CSTEP;
    __syncthreads();
    // ---- stage 128 contexts: one row per 32-lane group per instruction ----
    {
      int toks[8];
#pragma unroll
      for (int i = 0; i < 8; ++i) toks[i] = ctok[cb + i * 16 + grp];
#pragma unroll
      for (int i = 0; i < 8; ++i) {
        const int row = i * 16 + grp;
        const float4 v = *(const float4*)(emb + (size_t)toks[i] * D + 4 * l);
        uint2 pk = make_uint2(pack2(v.x, v.y), pack2(v.z, v.w));
        *(uint2*)(&sCt[row * SRW + 4 * l]) = pk;
      }
    }
    __syncthreads();

    // ---- 8 tiles of 16 contexts: 4 MFMAs (K=128) + selection ----
#pragma unroll
    for (int tt = 0; tt < 8; ++tt) {
      f32x4 acc = {0.f, 0.f, 0.f, 0.f};
      const int m = 16 * tt + n;  // context row in staged block
#pragma unroll
      for (int kk = 0; kk < 4; ++kk) {
        const bf16x8 af = *(const bf16x8*)(&sCt[m * SRW + 8 * (4 * kk + qq)]);
        acc = __builtin_amdgcn_mfma_f32_16x16x32_bf16(af, bq[kk], acc, 0, 0, 0);
      }
      // C/D: col=lane&15 (query), row = 4*qq + r (context within tile)
      const f32x4 cv = *(const f32x4*)(&scn2[st * CSTEP + 16 * tt + 4 * qq]);
      const int ibase = cb + 16 * tt + 4 * qq;
      const float s0 = fmaf(-2.f, acc[0], cv[0]);
      const float s1 = fmaf(-2.f, acc[1], cv[1]);
      const float s2 = fmaf(-2.f, acc[2], cv[2]);
      const float s3 = fmaf(-2.f, acc[3], cv[3]);
      const float mab = fminf(s0, s1); const int iab = (s1 < s0) ? ibase + 1 : ibase;
      const float mcd = fminf(s2, s3); const int icd = (s3 < s2) ? ibase + 3 : ibase + 2;
      const float mv = fminf(mab, mcd); const int mi = (mcd < mab) ? icd : iab;
      if (mv < bmax) INSERT(mv, mi);
      if (s0 < bmax && ibase + 0 != mi) INSERT(s0, ibase + 0);
      if (s1 < bmax && ibase + 1 != mi) INSERT(s1, ibase + 1);
      if (s2 < bmax && ibase + 2 != mi) INSERT(s2, ibase + 2);
      if (s3 < bmax && ibase + 3 != mi) INSERT(s3, ibase + 3);
    }
  }

  // ---- block merge: 4 qq-lanes x 8 slots -> 32 cands per query ----
  __syncthreads();
  float2* mb = (float2*)sCt;  // 128 queries x 33 (padded) float2 = 33792 B
  const int qlocal = wid * 16 + n;
#pragma unroll
  for (int t = 0; t < 8; ++t)
    mb[qlocal * 33 + qq * 8 + t] = make_float2(bs[t], __int_as_float(bi[t]));
  __syncthreads();

  // ---- quad-parallel top-8 of 32: lanes {L, L^16, L^32, L^48} per query ----
  const int sl = lane >> 4;            // candidate-slot group 0..3
  const int qrow2 = wid * 16 + n;      // query (same n as compute, any map ok)
  float v8[8]; int vi8[8];
#pragma unroll
  for (int j = 0; j < 8; ++j) {
    const float2 cd = mb[qrow2 * 33 + sl * 8 + j];
    v8[j] = cd.x; vi8[j] = __float_as_int(cd.y);
  }
  unsigned cons = 0;
  float rv0 = FINF, rv1 = FINF; int ri0 = 0, ri1 = 0;
#pragma unroll
  for (int t = 0; t < TOPN; ++t) {
    float lmin = FINF; int li = 0x7fffffff; int ls = 0;
#pragma unroll
    for (int j = 0; j < 8; ++j) {
      const bool take = !((cons >> j) & 1u) && (v8[j] < lmin);
      lmin = take ? v8[j] : lmin;
      li = take ? vi8[j] : li;
      ls = take ? j : ls;
    }
    float m = lmin; int pidx = li; int pwho = (sl << 3) | ls;
#pragma unroll
    for (int off = 16; off <= 32; off <<= 1) {
      const float om = __shfl_xor(m, off, 64);
      const int oi = __shfl_xor(pidx, off, 64);
      const int ow = __shfl_xor(pwho, off, 64);
      const bool better = (om < m) || (om == m && oi < pidx);
      m = better ? om : m; pidx = better ? oi : pidx; pwho = better ? ow : pwho;
    }
    if ((pwho >> 3) == sl) cons |= 1u << (pwho & 7);
    if (sl == (t >> 1)) {
      if ((t & 1) == 0) { rv0 = m; ri0 = pidx; } else { rv1 = m; ri1 = pidx; }
    }
  }
  const int q = qbase + qrow2;
  partials[(size_t)q * NCANDTOT + chunk * 8 + 2 * sl + 0] = make_float2(rv0, __int_as_float(ri0));
  partials[(size_t)q * NCANDTOT + chunk * 8 + 2 * sl + 1] = make_float2(rv1, __int_as_float(ri1));
#undef INSERT
}

// ---------------------------------------------------------------------------
// Kernel 4: per-query merge of 1024 candidates -> top-16, one WAVE per query.
__global__ __launch_bounds__(256) void merge16_kernel(const float2* __restrict__ partials,
                                                      int* __restrict__ cand) {
  const int lane = threadIdx.x & 63;
  const int q = blockIdx.x * 4 + (threadIdx.x >> 6);  // 4 waves per block

  float v[16]; int vi[16];
  const float2* pq = partials + (size_t)q * NCANDTOT;
#pragma unroll
  for (int j = 0; j < 16; ++j) {
    const float2 cd = pq[64 * j + lane];  // coalesced 512B per wave-load
    v[j] = cd.x; vi[j] = __float_as_int(cd.y);
  }

  unsigned consumed = 0;
  int myc = 0;
#pragma unroll
  for (int t = 0; t < NCAND; ++t) {
    float lmin = FINF; int li = 0x7fffffff; int ls = 0;
#pragma unroll
    for (int j = 0; j < 16; ++j) {
      const bool take = !((consumed >> j) & 1u) && (v[j] < lmin);
      lmin = take ? v[j] : lmin;
      li = take ? vi[j] : li;
      ls = take ? j : ls;
    }
    float m = lmin; int pidx = li; int pwho = (lane << 4) | ls;
#pragma unroll
    for (int off = 32; off; off >>= 1) {
      const float om = __shfl_xor(m, off, 64);
      const int oi = __shfl_xor(pidx, off, 64);
      const int ow = __shfl_xor(pwho, off, 64);
      const bool better = (om < m) || (om == m && oi < pidx);
      m = better ? om : m; pidx = better ? oi : pidx; pwho = better ? ow : pwho;
    }
    if ((pwho >> 4) == lane) consumed |= 1u << (pwho & 15);
    if (lane == t) myc = pidx;
  }
  if (lane < NCAND) cand[q * NCAND + lane] = myc;
}

// ---------------------------------------------------------------------------
// Kernel 5: f64 refine — exact d^2 and dp = qp.c per (q, cand).
__global__ __launch_bounds__(256) void refine_kernel(const int* __restrict__ cand,
                                                     const int* __restrict__ qtok,
                                                     const int* __restrict__ ctok,
                                                     const float* __restrict__ emb,
                                                     const float* __restrict__ qp,
                                                     double* __restrict__ rd2,
                                                     double* __restrict__ rdp) {
  const int g = threadIdx.x >> 5, l = threadIdx.x & 31;
  const int p = blockIdx.x * 8 + g;          // 0 .. NQ*NCAND-1
  const int q = p >> 4, n = p & (NCAND - 1);
  const int idx = cand[q * NCAND + n];
  const int tc = ctok[idx], tq = qtok[q];
  const float4 c4 = *(const float4*)(emb + (size_t)tc * D + 4 * l);
  const float4 q4 = *(const float4*)(emb + (size_t)tq * D + 4 * l);
  const float4 p4 = *(const float4*)(qp + (size_t)q * D + 4 * l);
  const double dx = (double)q4.x - (double)c4.x, dy = (double)q4.y - (double)c4.y;
  const double dz = (double)q4.z - (double)c4.z, dw = (double)q4.w - (double)c4.w;
  double dd = dx * dx + dy * dy + dz * dz + dw * dw;
  double pp = (double)p4.x * (double)c4.x + (double)p4.y * (double)c4.y +
              (double)p4.z * (double)c4.z + (double)p4.w * (double)c4.w;
#pragma unroll
  for (int off = 16; off; off >>= 1) {
    dd += __shfl_xor(dd, off, 32);
    pp += __shfl_xor(pp, off, 32);
  }
  if (l == 0) { rd2[q * NCAND + n] = dd; rdp[q * NCAND + n] = pp; }
}

// ---------------------------------------------------------------------------
// Kernel 6: exact top-8 of 16 by f64 d^2, logits + softmax-max (f64).
__global__ __launch_bounds__(64) void final_kernel(const double* __restrict__ rd2,
                                                   const double* __restrict__ rdp,
                                                   const int* __restrict__ cand,
                                                   float* __restrict__ importance) {
  const int q = blockIdx.x * 64 + threadIdx.x;
  double d2[NCAND], dp[NCAND]; int id[NCAND]; bool used[NCAND];
#pragma unroll
  for (int n = 0; n < NCAND; ++n) {
    d2[n] = rd2[q * NCAND + n];
    dp[n] = rdp[q * NCAND + n];
    id[n] = cand[q * NCAND + n];
    used[n] = false;
  }
  double lg[TOPN];
  for (int t = 0; t < TOPN; ++t) {
    int best = -1;
    for (int n = 0; n < NCAND; ++n) {
      if (used[n]) continue;
      if (best < 0 || d2[n] < d2[best] ||
          (d2[n] == d2[best] && id[n] < id[best])) best = n;
    }
    used[best] = true;
    lg[t] = dp[best] * 0.08838834764831843 - sqrt(d2[best] + 1e-12);
  }
  double m = lg[0];
#pragma unroll
  for (int t = 1; t < TOPN; ++t) m = fmax(m, lg[t]);
  double sum = 0.0;
#pragma unroll
  for (int t = 0; t < TOPN; ++t) sum += exp(lg[t] - m);
  importance[q] = (float)(1.0 / sum);  // max softmax = 1/sum
}

// ---------------------------------------------------------------------------
// Kernel 7: softmax over Lq per batch, write reconstructed query (f64 internal).
__global__ __launch_bounds__(128) void out_kernel(const float* __restrict__ importance,
                                                  const int* __restrict__ qtok,
                                                  float* __restrict__ out) {
  const int b = blockIdx.x, i = threadIdx.x;  // 4 blocks x 128 threads
  __shared__ double sred[2];
  const double v = (double)importance[b * 128 + i];
  double m = v;
#pragma unroll
  for (int off = 32; off; off >>= 1) m = fmax(m, __shfl_xor(m, off, 64));
  if ((i & 63) == 0) sred[i >> 6] = m;
  __syncthreads();
  const double M = fmax(sred[0], sred[1]);
  const double e = exp(v - M);
  double s = e;
#pragma unroll
  for (int off = 32; off; off >>= 1) s += __shfl_xor(s, off, 64);
  __syncthreads();
  if ((i & 63) == 0) sred[i >> 6] = s;
  __syncthreads();
  const double S = sred[0] + sred[1];
  out[b * 128 + i] = (float)((double)qtok[b * 128 + i] * (e / S) * 128.0);
}

// ---------------------------------------------------------------------------
extern "C" void kernel_launch(void* const* d_in, const int* in_sizes, int n_in,
                              void* d_out, int out_size, void* d_ws, size_t ws_size,
                              hipStream_t stream) {
  const int* qtok = (const int*)d_in[0];
  const int* ctok = (const int*)d_in[1];
  const float* emb = (const float*)d_in[2];
  const float* W = (const float*)d_in[3];
  const float* bvec = (const float*)d_in[4];
  float* out = (float*)d_out;

  char* ws = (char*)d_ws;
  double* rd2 = (double*)ws;                       // 64 KB (8B-aligned first)
  double* rdp = rd2 + NQ * NCAND;                  // 64 KB
  float* cn2 = (float*)(rdp + NQ * NCAND);         // 256 KB
  float* qp = cn2 + LCTX;                          // 256 KB
  float* imp = qp + (size_t)NQ * D;                // 2 KB
  int* cand = (int*)(imp + NQ);                    // 32 KB
  float2* partials = (float2*)(cand + NQ * NCAND); // 4 MB

  cn2_kernel<<<LCTX / 8, 256, 0, stream>>>(ctok, emb, cn2);
  qprep_kernel<<<NQ, 128, 0, stream>>>(qtok, emb, W, bvec, qp);
  dist_topk_kernel<<<dim3(NCH, NQT), 512, 0, stream>>>(ctok, qtok, emb, cn2, partials);
  merge16_kernel<<<NQ / 4, 256, 0, stream>>>(partials, cand);
  refine_kernel<<<NQ * NCAND / 8, 256, 0, stream>>>(cand, qtok, ctok, emb, qp, rd2, rdp);
  final_kernel<<<NQ / 64, 64, 0, stream>>>(rd2, rdp, cand, imp);
  out_kernel<<<4, 128, 0, stream>>>(imp, qtok, out);
}

// Round 9
// 199.467 us; speedup vs baseline: 38.1832x; 1.0803x over previous
//
#include <hip/hip_runtime.h>
#include <math.h>

// Problem constants
#define D      128
#define NQ     512          // B * LQ = 4 * 128
#define LCTX   65536
#define TOPN   8
#define NCAND  16           // coarse candidates refined in f64
// Distance-kernel tiling
#define QT     64           // queries per block (4 waves x 16)
#define CCHUNK 512          // contexts per block
#define CSTEP  128          // contexts staged per LDS step
#define NCH    (LCTX / CCHUNK)   // 128 chunks
#define NCANDTOT (NCH * 8)       // 1024 coarse candidates per query
#define NQT    (NQ / QT)         // 8 query tiles
#define NROWS  (LCTX + NQ)       // packed table rows (contexts then queries)
#define FINF   3.0e38f

typedef __attribute__((ext_vector_type(8))) __bf16 bf16x8;
typedef __attribute__((ext_vector_type(4))) float f32x4;

// pack two f32 -> two bf16 (round-to-nearest-ish; coarse path only)
static __device__ __forceinline__ unsigned pack2(float a, float b) {
  const unsigned ua = (__float_as_uint(a) + 0x8000u) >> 16;
  const unsigned ub = (__float_as_uint(b) + 0x8000u) & 0xffff0000u;
  return ua | ub;
}

// ---------------------------------------------------------------------------
// Kernel 1: gather+pack ALL rows (contexts + queries) to bf16 ONCE, fused with
// ||c||^2.  R8 post-mortem: in-loop gather+pack was ~half the hot-kernel VALU
// and was redone NQT x per chunk.  cemb rows are chunk-XOR-pre-swizzled
// (chunk c stored at slot c ^ (row&7)) so global_load_lds deposits the
// swizzled layout into LDS with zero shader work.
__global__ __launch_bounds__(256) void pack_kernel(const int* __restrict__ ctok,
                                                   const int* __restrict__ qtok,
                                                   const float* __restrict__ emb,
                                                   unsigned short* __restrict__ cemb,
                                                   float* __restrict__ cn2) {
  const int g = threadIdx.x >> 5, l = threadIdx.x & 31;
  const int row = blockIdx.x * 8 + g;  // grid exact: NROWS/8
  const int tok = (row < LCTX) ? ctok[row] : qtok[row - LCTX];
  const float4 v = *(const float4*)(emb + (size_t)tok * D + 4 * l);
  float p = v.x * v.x + v.y * v.y + v.z * v.z + v.w * v.w;
#pragma unroll
  for (int off = 16; off; off >>= 1) p += __shfl_xor(p, off, 32);
  if (l == 0 && row < LCTX) cn2[row] = p;
  const int c = l >> 1, h = l & 1;       // 16-B chunk, half-chunk
  const int pch = c ^ (row & 7);         // pre-swizzle
  uint2 pk = make_uint2(pack2(v.x, v.y), pack2(v.z, v.w));
  *(uint2*)(&cemb[(size_t)row * D + pch * 8 + h * 4]) = pk;
}

// ---------------------------------------------------------------------------
// Kernel 2: qp = q @ W + b.  One block (128 thr) per query.  fp32.
__global__ __launch_bounds__(128) void qprep_kernel(const int* __restrict__ qtok,
                                                    const float* __restrict__ emb,
                                                    const float* __restrict__ W,
                                                    const float* __restrict__ bvec,
                                                    float* __restrict__ qp) {
  const int q = blockIdx.x;
  const int d = threadIdx.x;  // 0..127
  __shared__ float sq[D];
  const int tok = qtok[q];
  sq[d] = emb[(size_t)tok * D + d];
  __syncthreads();
  float acc = bvec[d];
  for (int k = 0; k < D; ++k) acc = fmaf(sq[k], W[k * D + d], acc);
  qp[(size_t)q * D + d] = acc;
}

// ---------------------------------------------------------------------------
// Kernel 3: coarse scores via bf16 MFMA + streaming top-8 per (query, chunk).
// Grid (NCH, NQT), 256 threads = 4 waves; wave w owns queries qbase+16w..+15,
// one query per lane-column -> per-lane top-8 state is 16 VGPRs.
// Staging is pure DMA: global_load_lds dwordx4 from pre-packed cemb (per-lane
// address linear in lane, LDS dest = uniform base + lane*16 -- the HW
// constraint).  4 blocks/CU (34 KB LDS) so staging of one block overlaps
// compute of another.
__global__ __launch_bounds__(256, 4) void dist_topk_kernel(
    const unsigned short* __restrict__ cemb, const float* __restrict__ cn2,
    float2* __restrict__ partials) {
  __shared__ __align__(16) unsigned short sCt[CSTEP * D];  // 32 KB
  __shared__ __align__(16) float scn2[CCHUNK];             // 2 KB

  const int tid = threadIdx.x;
  const int wid = tid >> 6, lane = tid & 63;
  const int n = lane & 15, qq = lane >> 4;   // query col, k-quad / C-row group
  const int chunk = blockIdx.x, qtile = blockIdx.y;
  const int qbase = qtile * QT, cbase0 = chunk * CCHUNK;

  scn2[tid] = cn2[cbase0 + tid];
  scn2[tid + 256] = cn2[cbase0 + tid + 256];

  // ---- stage Q tile (rows LCTX+qbase..+63) into sCt rows 0..63 via DMA ----
  {
    const unsigned short* qrowbase = cemb + (size_t)(LCTX + qbase) * D;
#pragma unroll
    for (int j = 0; j < 4; ++j) {
      const int r0 = wid * 16 + j * 4;  // 4 rows per inst (64 lanes x 16 B)
      const unsigned short* gp = qrowbase + r0 * D + lane * 8;
      __builtin_amdgcn_global_load_lds(
          (const __attribute__((address_space(1))) unsigned int*)gp,
          (__attribute__((address_space(3))) unsigned int*)&sCt[r0 * D], 16, 0, 0);
    }
  }
  __syncthreads();

  // ---- B-fragments from swizzled LDS: B[n][k=32kk+8qq+j] ----
  bf16x8 bq[4];
  {
    const int rq = wid * 16 + n;
#pragma unroll
    for (int kk = 0; kk < 4; ++kk)
      bq[kk] = *(const bf16x8*)(&sCt[rq * D + 8 * ((4 * kk + qq) ^ (rq & 7))]);
  }

  // ---- per-lane top-8 (one query) ----
  float bs[8]; int bi[8]; float bmax = FINF;
#pragma unroll
  for (int t = 0; t < 8; ++t) { bs[t] = FINF; bi[t] = 0; }

#define INSERT(V, I) do { \
    bool done_ = false; \
    _Pragma("unroll") \
    for (int t_ = 0; t_ < 8; ++t_) { \
      const bool hit_ = (!done_) && (bs[t_] == bmax); \
      if (hit_) { bs[t_] = (V); bi[t_] = (I); done_ = true; } \
    } \
    float mx_ = bs[0]; \
    _Pragma("unroll") \
    for (int t_ = 1; t_ < 8; ++t_) mx_ = fmaxf(mx_, bs[t_]); \
    bmax = mx_; \
  } while (0)

  for (int st = 0; st < CCHUNK / CSTEP; ++st) {
    const int cb = cbase0 + st * CSTEP;
    __syncthreads();  // previous step's LDS reads done in all waves
    // ---- stage 128 context rows: 8 DMA insts per wave, zero pack VALU ----
    {
      const unsigned short* crowbase = cemb + (size_t)cb * D;
#pragma unroll
      for (int j = 0; j < 8; ++j) {
        const int r0 = wid * 32 + j * 4;
        const unsigned short* gp = crowbase + r0 * D + lane * 8;
        __builtin_amdgcn_global_load_lds(
            (const __attribute__((address_space(1))) unsigned int*)gp,
            (__attribute__((address_space(3))) unsigned int*)&sCt[r0 * D], 16, 0, 0);
      }
    }
    __syncthreads();  // drains vmcnt (compiler-inserted before s_barrier)

    // ---- 8 tiles of 16 contexts: 4 MFMAs (K=128) + selection ----
#pragma unroll
    for (int tt = 0; tt < 8; ++tt) {
      f32x4 acc = {0.f, 0.f, 0.f, 0.f};
      const int m = 16 * tt + n;  // LDS row; (global row)&7 == m&7 == n&7
#pragma unroll
      for (int kk = 0; kk < 4; ++kk) {
        const bf16x8 af = *(const bf16x8*)(&sCt[m * D + 8 * ((4 * kk + qq) ^ (n & 7))]);
        acc = __builtin_amdgcn_mfma_f32_16x16x32_bf16(af, bq[kk], acc, 0, 0, 0);
      }
      // C/D: col=lane&15 (query), row = 4*qq + r (context within tile)
      const f32x4 cv = *(const f32x4*)(&scn2[st * CSTEP + 16 * tt + 4 * qq]);
      const int ibase = cb + 16 * tt + 4 * qq;
      const float s0 = fmaf(-2.f, acc[0], cv[0]);
      const float s1 = fmaf(-2.f, acc[1], cv[1]);
      const float s2 = fmaf(-2.f, acc[2], cv[2]);
      const float s3 = fmaf(-2.f, acc[3], cv[3]);
      const float mab = fminf(s0, s1); const int iab = (s1 < s0) ? ibase + 1 : ibase;
      const float mcd = fminf(s2, s3); const int icd = (s3 < s2) ? ibase + 3 : ibase + 2;
      const float mv = fminf(mab, mcd); const int mi = (mcd < mab) ? icd : iab;
      if (mv < bmax) INSERT(mv, mi);
      if (s0 < bmax && ibase + 0 != mi) INSERT(s0, ibase + 0);
      if (s1 < bmax && ibase + 1 != mi) INSERT(s1, ibase + 1);
      if (s2 < bmax && ibase + 2 != mi) INSERT(s2, ibase + 2);
      if (s3 < bmax && ibase + 3 != mi) INSERT(s3, ibase + 3);
    }
  }

  // ---- block merge: 4 qq-lanes x 8 slots -> 32 cands per query ----
  __syncthreads();
  float2* mb = (float2*)sCt;  // 64 queries x 33 (padded) float2 = 16.9 KB
  const int qlocal = wid * 16 + n;
#pragma unroll
  for (int t = 0; t < 8; ++t)
    mb[qlocal * 33 + qq * 8 + t] = make_float2(bs[t], __int_as_float(bi[t]));
  __syncthreads();

  // ---- quad-parallel top-8 of 32: lanes {L, L^16, L^32, L^48} per query ----
  const int sl = lane >> 4;            // candidate-slot group 0..3
  const int qrow2 = wid * 16 + n;
  float v8[8]; int vi8[8];
#pragma unroll
  for (int j = 0; j < 8; ++j) {
    const float2 cd = mb[qrow2 * 33 + sl * 8 + j];
    v8[j] = cd.x; vi8[j] = __float_as_int(cd.y);
  }
  unsigned cons = 0;
  float rv0 = FINF, rv1 = FINF; int ri0 = 0, ri1 = 0;
#pragma unroll
  for (int t = 0; t < TOPN; ++t) {
    float lmin = FINF; int li = 0x7fffffff; int ls = 0;
#pragma unroll
    for (int j = 0; j < 8; ++j) {
      const bool take = !((cons >> j) & 1u) && (v8[j] < lmin);
      lmin = take ? v8[j] : lmin;
      li = take ? vi8[j] : li;
      ls = take ? j : ls;
    }
    float m = lmin; int pidx = li; int pwho = (sl << 3) | ls;
#pragma unroll
    for (int off = 16; off <= 32; off <<= 1) {
      const float om = __shfl_xor(m, off, 64);
      const int oi = __shfl_xor(pidx, off, 64);
      const int ow = __shfl_xor(pwho, off, 64);
      const bool better = (om < m) || (om == m && oi < pidx);
      m = better ? om : m; pidx = better ? oi : pidx; pwho = better ? ow : pwho;
    }
    if ((pwho >> 3) == sl) cons |= 1u << (pwho & 7);
    if (sl == (t >> 1)) {
      if ((t & 1) == 0) { rv0 = m; ri0 = pidx; } else { rv1 = m; ri1 = pidx; }
    }
  }
  const int q = qbase + qrow2;
  partials[(size_t)q * NCANDTOT + chunk * 8 + 2 * sl + 0] = make_float2(rv0, __int_as_float(ri0));
  partials[(size_t)q * NCANDTOT + chunk * 8 + 2 * sl + 1] = make_float2(rv1, __int_as_float(ri1));
#undef INSERT
}

// ---------------------------------------------------------------------------
// Kernel 4 (fused merge16 + f64 refine + final): one WAVE per query.
// Phase 1: top-16 of 1024 coarse candidates (shfl argmin, idx tie-break).
// Phase 2: exact f64 d^2 and dp = qp.c, 4 lanes per candidate.
// Phase 3: lane 0 serial exact top-8-of-16 + logits + max-softmax (f64).
__global__ __launch_bounds__(256) void select_kernel(
    const float2* __restrict__ partials, const int* __restrict__ qtok,
    const int* __restrict__ ctok, const float* __restrict__ emb,
    const float* __restrict__ qp, float* __restrict__ importance) {
  __shared__ double sd2[4][NCAND];
  __shared__ double sdp[4][NCAND];
  __shared__ int sid[4][NCAND];
  const int w = threadIdx.x >> 6, lane = threadIdx.x & 63;
  const int q = blockIdx.x * 4 + w;

  // ---- phase 1: top-16 of 1024 ----
  float v[16]; int vi[16];
  const float2* pq = partials + (size_t)q * NCANDTOT;
#pragma unroll
  for (int j = 0; j < 16; ++j) {
    const float2 cd = pq[64 * j + lane];  // coalesced 512B per wave-load
    v[j] = cd.x; vi[j] = __float_as_int(cd.y);
  }
  unsigned consumed = 0;
  int myc = 0;
#pragma unroll
  for (int t = 0; t < NCAND; ++t) {
    float lmin = FINF; int li = 0x7fffffff; int ls = 0;
#pragma unroll
    for (int j = 0; j < 16; ++j) {
      const bool take = !((consumed >> j) & 1u) && (v[j] < lmin);
      lmin = take ? v[j] : lmin;
      li = take ? vi[j] : li;
      ls = take ? j : ls;
    }
    float m = lmin; int pidx = li; int pwho = (lane << 4) | ls;
#pragma unroll
    for (int off = 32; off; off >>= 1) {
      const float om = __shfl_xor(m, off, 64);
      const int oi = __shfl_xor(pidx, off, 64);
      const int ow = __shfl_xor(pwho, off, 64);
      const bool better = (om < m) || (om == m && oi < pidx);
      m = better ? om : m; pidx = better ? oi : pidx; pwho = better ? ow : pwho;
    }
    if ((pwho >> 4) == lane) consumed |= 1u << (pwho & 15);
    if (lane == t) myc = pidx;
  }

  // ---- phase 2: f64 refine; candidate c = lane>>2, 32 dims per lane ----
  const int c = lane >> 2, sub = lane & 3;
  const int idx = __shfl(myc, c, 64);   // broadcast candidate c from lane c
  const int tc = ctok[idx];
  const int tq = qtok[q];
  const float* crow = emb + (size_t)tc * D + sub * 32;
  const float* qrow = emb + (size_t)tq * D + sub * 32;
  const float* prow = qp + (size_t)q * D + sub * 32;
  double dd = 0.0, pp = 0.0;
#pragma unroll
  for (int kk = 0; kk < 8; ++kk) {
    const float4 cv = *(const float4*)(crow + 4 * kk);
    const float4 qv = *(const float4*)(qrow + 4 * kk);
    const float4 pv = *(const float4*)(prow + 4 * kk);
    const double dx = (double)qv.x - (double)cv.x, dy = (double)qv.y - (double)cv.y;
    const double dz = (double)qv.z - (double)cv.z, dw = (double)qv.w - (double)cv.w;
    dd += dx * dx + dy * dy + dz * dz + dw * dw;
    pp += (double)pv.x * (double)cv.x + (double)pv.y * (double)cv.y +
          (double)pv.z * (double)cv.z + (double)pv.w * (double)cv.w;
  }
  dd += __shfl_xor(dd, 1, 64); dd += __shfl_xor(dd, 2, 64);
  pp += __shfl_xor(pp, 1, 64); pp += __shfl_xor(pp, 2, 64);
  if (sub == 0) { sd2[w][c] = dd; sdp[w][c] = pp; sid[w][c] = idx; }

  // ---- phase 3: lane 0 serial (same wave wrote LDS; lgkmcnt ordering) ----
  if (lane == 0) {
    bool used[NCAND];
#pragma unroll
    for (int n2 = 0; n2 < NCAND; ++n2) used[n2] = false;
    double lg[TOPN];
    for (int t = 0; t < TOPN; ++t) {
      int best = -1;
      for (int n2 = 0; n2 < NCAND; ++n2) {
        if (used[n2]) continue;
        if (best < 0 || sd2[w][n2] < sd2[w][best] ||
            (sd2[w][n2] == sd2[w][best] && sid[w][n2] < sid[w][best])) best = n2;
      }
      used[best] = true;
      lg[t] = sdp[w][best] * 0.08838834764831843 - sqrt(sd2[w][best] + 1e-12);
    }
    double m = lg[0];
#pragma unroll
    for (int t = 1; t < TOPN; ++t) m = fmax(m, lg[t]);
    double sum = 0.0;
#pragma unroll
    for (int t = 0; t < TOPN; ++t) sum += exp(lg[t] - m);
    importance[q] = (float)(1.0 / sum);  // max softmax = 1/sum
  }
}

// ---------------------------------------------------------------------------
// Kernel 5: softmax over Lq per batch, write reconstructed query (f64 internal).
__global__ __launch_bounds__(128) void out_kernel(const float* __restrict__ importance,
                                                  const int* __restrict__ qtok,
                                                  float* __restrict__ out) {
  const int b = blockIdx.x, i = threadIdx.x;  // 4 blocks x 128 threads
  __shared__ double sred[2];
  const double v = (double)importance[b * 128 + i];
  double m = v;
#pragma unroll
  for (int off = 32; off; off >>= 1) m = fmax(m, __shfl_xor(m, off, 64));
  if ((i & 63) == 0) sred[i >> 6] = m;
  __syncthreads();
  const double M = fmax(sred[0], sred[1]);
  const double e = exp(v - M);
  double s = e;
#pragma unroll
  for (int off = 32; off; off >>= 1) s += __shfl_xor(s, off, 64);
  __syncthreads();
  if ((i & 63) == 0) sred[i >> 6] = s;
  __syncthreads();
  const double S = sred[0] + sred[1];
  out[b * 128 + i] = (float)((double)qtok[b * 128 + i] * (e / S) * 128.0);
}

// ---------------------------------------------------------------------------
extern "C" void kernel_launch(void* const* d_in, const int* in_sizes, int n_in,
                              void* d_out, int out_size, void* d_ws, size_t ws_size,
                              hipStream_t stream) {
  const int* qtok = (const int*)d_in[0];
  const int* ctok = (const int*)d_in[1];
  const float* emb = (const float*)d_in[2];
  const float* W = (const float*)d_in[3];
  const float* bvec = (const float*)d_in[4];
  float* out = (float*)d_out;

  char* ws = (char*)d_ws;
  float* cn2 = (float*)ws;                               // 256 KB
  float* qp = cn2 + LCTX;                                // 256 KB
  float* imp = qp + (size_t)NQ * D;                      // 2 KB
  unsigned short* cemb = (unsigned short*)(imp + NQ);    // 16.9 MB (16B-aligned)
  float2* partials = (float2*)(cemb + (size_t)NROWS * D);// 4.2 MB
  // total ws ~= 21.6 MB

  pack_kernel<<<NROWS / 8, 256, 0, stream>>>(ctok, qtok, emb, cemb, cn2);
  qprep_kernel<<<NQ, 128, 0, stream>>>(qtok, emb, W, bvec, qp);
  dist_topk_kernel<<<dim3(NCH, NQT), 256, 0, stream>>>(cemb, cn2, partials);
  select_kernel<<<NQ / 4, 256, 0, stream>>>(partials, qtok, ctok, emb, qp, imp);
  out_kernel<<<4, 128, 0, stream>>>(imp, qtok, out);
}

// Round 10
// 158.241 us; speedup vs baseline: 48.1312x; 1.2605x over previous
//
#include <hip/hip_runtime.h>
#include <math.h>

// Problem constants
#define D      128
#define NQ     512          // B * LQ = 4 * 128
#define LCTX   65536
#define TOPN   8
#define NCAND  16           // coarse candidates refined in f64
// Distance-kernel tiling
#define QT     64           // queries per block (4 waves x 16)
#define CCHUNK 512          // contexts per block
#define CSTEP  128          // contexts staged per LDS step
#define NCH    (LCTX / CCHUNK)    // 128 chunks
#define PERCHUNK 16               // candidates stored per (query, chunk)
#define NCANDTOT (NCH * PERCHUNK) // 2048 coarse candidates per query
#define NQT    (NQ / QT)          // 8 query tiles
#define NROWS  (LCTX + NQ)        // packed table rows (contexts then queries)
#define FINF   3.0e38f

typedef __attribute__((ext_vector_type(8))) __bf16 bf16x8;
typedef __attribute__((ext_vector_type(4))) float f32x4;

// pack two f32 -> two bf16 (round-to-nearest-ish; coarse path only)
static __device__ __forceinline__ unsigned pack2(float a, float b) {
  const unsigned ua = (__float_as_uint(a) + 0x8000u) >> 16;
  const unsigned ub = (__float_as_uint(b) + 0x8000u) & 0xffff0000u;
  return ua | ub;
}

// ---------------------------------------------------------------------------
// Kernel 1: gather+pack ALL rows (contexts + queries) to bf16 ONCE, fused with
// ||c||^2.  cemb rows are chunk-XOR-pre-swizzled (chunk c at slot c ^ (row&7))
// so global_load_lds deposits the swizzled layout with zero shader work.
__global__ __launch_bounds__(256) void pack_kernel(const int* __restrict__ ctok,
                                                   const int* __restrict__ qtok,
                                                   const float* __restrict__ emb,
                                                   unsigned short* __restrict__ cemb,
                                                   float* __restrict__ cn2) {
  const int g = threadIdx.x >> 5, l = threadIdx.x & 31;
  const int row = blockIdx.x * 8 + g;  // grid exact: NROWS/8
  const int tok = (row < LCTX) ? ctok[row] : qtok[row - LCTX];
  const float4 v = *(const float4*)(emb + (size_t)tok * D + 4 * l);
  float p = v.x * v.x + v.y * v.y + v.z * v.z + v.w * v.w;
#pragma unroll
  for (int off = 16; off; off >>= 1) p += __shfl_xor(p, off, 32);
  if (l == 0 && row < LCTX) cn2[row] = p;
  const int c = l >> 1, h = l & 1;       // 16-B chunk, half-chunk
  const int pch = c ^ (row & 7);         // pre-swizzle
  uint2 pk = make_uint2(pack2(v.x, v.y), pack2(v.z, v.w));
  *(uint2*)(&cemb[(size_t)row * D + pch * 8 + h * 4]) = pk;
}

// ---------------------------------------------------------------------------
// Kernel 2: qp = q @ W + b.  64 blocks x 256 thr; W staged once in LDS and
// amortized over 8 queries (R9: 512 tiny blocks re-streamed W per query).
__global__ __launch_bounds__(256) void qprep_kernel(const int* __restrict__ qtok,
                                                    const float* __restrict__ emb,
                                                    const float* __restrict__ W,
                                                    const float* __restrict__ bvec,
                                                    float* __restrict__ qp) {
  __shared__ float sW[D * D];   // 64 KB
  __shared__ float sq[8][D];    // 4 KB
  const int tid = threadIdx.x;
  const int qb = blockIdx.x * 8;
#pragma unroll
  for (int j = 0; j < 16; ++j) {
    const int i4 = j * 256 + tid;
    *(float4*)(&sW[i4 * 4]) = *(const float4*)(W + i4 * 4);
  }
  {
    const int r = tid >> 5, l = tid & 31;
    const int tok = qtok[qb + r];
    *(float4*)(&sq[r][4 * l]) = *(const float4*)(emb + (size_t)tok * D + 4 * l);
  }
  __syncthreads();
  const int d = tid & 127, qs = tid >> 7;  // thread handles queries qs,qs+2,qs+4,qs+6
  const float bv = bvec[d];
  float acc[4] = {bv, bv, bv, bv};
  for (int k = 0; k < D; ++k) {
    const float wv = sW[k * D + d];
#pragma unroll
    for (int i = 0; i < 4; ++i) acc[i] = fmaf(sq[2 * i + qs][k], wv, acc[i]);
  }
#pragma unroll
  for (int i = 0; i < 4; ++i) qp[(size_t)(qb + 2 * i + qs) * D + d] = acc[i];
}

// ---------------------------------------------------------------------------
// Kernel 3: coarse scores via bf16 MFMA + per-lane sorted top-4.
// R9 post-mortem: the top-8 replace-max insert machinery was ~2250 VALU
// insts/step/wave (30 of the 78 us).  Replacement: branchless sorted-ascending
// top-4 via v_med3_f32 ladder (~15 insts/candidate, bmax == bs[3] free), and
// the block-merge tail is deleted — 4 qq-lanes x 4 slots = 16 candidates per
// (query, chunk) are written directly.
__global__ __launch_bounds__(256, 4) void dist_topk_kernel(
    const unsigned short* __restrict__ cemb, const float* __restrict__ cn2,
    float2* __restrict__ partials) {
  __shared__ __align__(16) unsigned short sCt[CSTEP * D];  // 32 KB
  __shared__ __align__(16) float scn2[CCHUNK];             // 2 KB

  const int tid = threadIdx.x;
  const int wid = tid >> 6, lane = tid & 63;
  const int n = lane & 15, qq = lane >> 4;   // query col, k-quad / C-row group
  const int chunk = blockIdx.x, qtile = blockIdx.y;
  const int qbase = qtile * QT, cbase0 = chunk * CCHUNK;

  scn2[tid] = cn2[cbase0 + tid];
  scn2[tid + 256] = cn2[cbase0 + tid + 256];

  // ---- stage Q tile (rows LCTX+qbase..+63) into sCt rows 0..63 via DMA ----
  {
    const unsigned short* qrowbase = cemb + (size_t)(LCTX + qbase) * D;
#pragma unroll
    for (int j = 0; j < 4; ++j) {
      const int r0 = wid * 16 + j * 4;  // 4 rows per inst (64 lanes x 16 B)
      const unsigned short* gp = qrowbase + r0 * D + lane * 8;
      __builtin_amdgcn_global_load_lds(
          (const __attribute__((address_space(1))) unsigned int*)gp,
          (__attribute__((address_space(3))) unsigned int*)&sCt[r0 * D], 16, 0, 0);
    }
  }
  __syncthreads();

  // ---- B-fragments from swizzled LDS: B[n][k=32kk+8qq+j] ----
  bf16x8 bq[4];
  {
    const int rq = wid * 16 + n;
#pragma unroll
    for (int kk = 0; kk < 4; ++kk)
      bq[kk] = *(const bf16x8*)(&sCt[rq * D + 8 * ((4 * kk + qq) ^ (rq & 7))]);
  }

  // ---- per-lane sorted top-4 (ascending; bs[3] is the acceptance bound) ----
  float bs[4] = {FINF, FINF, FINF, FINF};
  int bi[4] = {0, 0, 0, 0};

  for (int st = 0; st < CCHUNK / CSTEP; ++st) {
    const int cb = cbase0 + st * CSTEP;
    __syncthreads();  // previous step's LDS reads done in all waves
    // ---- stage 128 context rows: 8 DMA insts per wave ----
    {
      const unsigned short* crowbase = cemb + (size_t)cb * D;
#pragma unroll
      for (int j = 0; j < 8; ++j) {
        const int r0 = wid * 32 + j * 4;
        const unsigned short* gp = crowbase + r0 * D + lane * 8;
        __builtin_amdgcn_global_load_lds(
            (const __attribute__((address_space(1))) unsigned int*)gp,
            (__attribute__((address_space(3))) unsigned int*)&sCt[r0 * D], 16, 0, 0);
      }
    }
    __syncthreads();

    // ---- 8 tiles of 16 contexts: 4 MFMAs (K=128) + branchless selection ----
#pragma unroll
    for (int tt = 0; tt < 8; ++tt) {
      f32x4 acc = {0.f, 0.f, 0.f, 0.f};
      const int m = 16 * tt + n;  // LDS row; (global row)&7 == n&7
#pragma unroll
      for (int kk = 0; kk < 4; ++kk) {
        const bf16x8 af = *(const bf16x8*)(&sCt[m * D + 8 * ((4 * kk + qq) ^ (n & 7))]);
        acc = __builtin_amdgcn_mfma_f32_16x16x32_bf16(af, bq[kk], acc, 0, 0, 0);
      }
      // C/D: col=lane&15 (query), row = 4*qq + r (context within tile)
      const f32x4 cv = *(const f32x4*)(&scn2[st * CSTEP + 16 * tt + 4 * qq]);
      const int ibase = cb + 16 * tt + 4 * qq;
#pragma unroll
      for (int r = 0; r < 4; ++r) {
        const float v = fmaf(-2.f, acc[r], cv[r]);
        const int iv = ibase + r;
        const bool c0 = v < bs[0], c1 = v < bs[1], c2 = v < bs[2], c3 = v < bs[3];
        const float nb0 = fminf(bs[0], v);
        const float nb1 = __builtin_amdgcn_fmed3f(v, bs[0], bs[1]);
        const float nb2 = __builtin_amdgcn_fmed3f(v, bs[1], bs[2]);
        const float nb3 = __builtin_amdgcn_fmed3f(v, bs[2], bs[3]);
        const int ni0 = c0 ? iv : bi[0];
        const int ni1 = c1 ? (c0 ? bi[0] : iv) : bi[1];
        const int ni2 = c2 ? (c1 ? bi[1] : iv) : bi[2];
        const int ni3 = c3 ? (c2 ? bi[2] : iv) : bi[3];
        bs[0] = nb0; bs[1] = nb1; bs[2] = nb2; bs[3] = nb3;
        bi[0] = ni0; bi[1] = ni1; bi[2] = ni2; bi[3] = ni3;
      }
    }
  }

  // ---- direct write-out: 16 candidates per (query, chunk), no merge ----
  const int q = qbase + wid * 16 + n;
  float2* dst = partials + (size_t)q * NCANDTOT + chunk * PERCHUNK + qq * 4;
#pragma unroll
  for (int t = 0; t < 4; ++t)
    dst[t] = make_float2(bs[t], __int_as_float(bi[t]));
}

// ---------------------------------------------------------------------------
// Kernel 4 (fused merge + f64 refine + final): one WAVE per query.
// Phase 1: top-16 of 2048 coarse candidates (shfl argmin, idx tie-break).
// Phase 2: exact f64 d^2 and dp = qp.c, 4 lanes per candidate.
// Phase 3: lane 0 serial exact top-8-of-16 + logits + max-softmax (f64).
__global__ __launch_bounds__(256) void select_kernel(
    const float2* __restrict__ partials, const int* __restrict__ qtok,
    const int* __restrict__ ctok, const float* __restrict__ emb,
    const float* __restrict__ qp, float* __restrict__ importance) {
  __shared__ double sd2[4][NCAND];
  __shared__ double sdp[4][NCAND];
  __shared__ int sid[4][NCAND];
  const int w = threadIdx.x >> 6, lane = threadIdx.x & 63;
  const int q = blockIdx.x * 4 + w;

  // ---- phase 1: top-16 of 2048 ----
  float v[32]; int vi[32];
  const float2* pq = partials + (size_t)q * NCANDTOT;
#pragma unroll
  for (int j = 0; j < 32; ++j) {
    const float2 cd = pq[64 * j + lane];  // coalesced 512B per wave-load
    v[j] = cd.x; vi[j] = __float_as_int(cd.y);
  }
  unsigned consumed = 0;
  int myc = 0;
#pragma unroll
  for (int t = 0; t < NCAND; ++t) {
    float lmin = FINF; int li = 0x7fffffff; int ls = 0;
#pragma unroll
    for (int j = 0; j < 32; ++j) {
      const bool take = !((consumed >> j) & 1u) && (v[j] < lmin);
      lmin = take ? v[j] : lmin;
      li = take ? vi[j] : li;
      ls = take ? j : ls;
    }
    float m = lmin; int pidx = li; int pwho = (lane << 5) | ls;
#pragma unroll
    for (int off = 32; off; off >>= 1) {
      const float om = __shfl_xor(m, off, 64);
      const int oi = __shfl_xor(pidx, off, 64);
      const int ow = __shfl_xor(pwho, off, 64);
      const bool better = (om < m) || (om == m && oi < pidx);
      m = better ? om : m; pidx = better ? oi : pidx; pwho = better ? ow : pwho;
    }
    if ((pwho >> 5) == lane) consumed |= 1u << (pwho & 31);
    if (lane == t) myc = pidx;
  }

  // ---- phase 2: f64 refine; candidate c = lane>>2, 32 dims per lane ----
  const int c = lane >> 2, sub = lane & 3;
  const int idx = __shfl(myc, c, 64);   // broadcast candidate c from lane c
  const int tc = ctok[idx];
  const int tq = qtok[q];
  const float* crow = emb + (size_t)tc * D + sub * 32;
  const float* qrow = emb + (size_t)tq * D + sub * 32;
  const float* prow = qp + (size_t)q * D + sub * 32;
  double dd = 0.0, pp = 0.0;
#pragma unroll
  for (int kk = 0; kk < 8; ++kk) {
    const float4 cv = *(const float4*)(crow + 4 * kk);
    const float4 qv = *(const float4*)(qrow + 4 * kk);
    const float4 pv = *(const float4*)(prow + 4 * kk);
    const double dx = (double)qv.x - (double)cv.x, dy = (double)qv.y - (double)cv.y;
    const double dz = (double)qv.z - (double)cv.z, dw = (double)qv.w - (double)cv.w;
    dd += dx * dx + dy * dy + dz * dz + dw * dw;
    pp += (double)pv.x * (double)cv.x + (double)pv.y * (double)cv.y +
          (double)pv.z * (double)cv.z + (double)pv.w * (double)cv.w;
  }
  dd += __shfl_xor(dd, 1, 64); dd += __shfl_xor(dd, 2, 64);
  pp += __shfl_xor(pp, 1, 64); pp += __shfl_xor(pp, 2, 64);
  if (sub == 0) { sd2[w][c] = dd; sdp[w][c] = pp; sid[w][c] = idx; }

  // ---- phase 3: lane 0 serial (same wave wrote LDS; lgkmcnt ordering) ----
  if (lane == 0) {
    bool used[NCAND];
#pragma unroll
    for (int n2 = 0; n2 < NCAND; ++n2) used[n2] = false;
    double lg[TOPN];
    for (int t = 0; t < TOPN; ++t) {
      int best = -1;
      for (int n2 = 0; n2 < NCAND; ++n2) {
        if (used[n2]) continue;
        if (best < 0 || sd2[w][n2] < sd2[w][best] ||
            (sd2[w][n2] == sd2[w][best] && sid[w][n2] < sid[w][best])) best = n2;
      }
      used[best] = true;
      lg[t] = sdp[w][best] * 0.08838834764831843 - sqrt(sd2[w][best] + 1e-12);
    }
    double m = lg[0];
#pragma unroll
    for (int t = 1; t < TOPN; ++t) m = fmax(m, lg[t]);
    double sum = 0.0;
#pragma unroll
    for (int t = 0; t < TOPN; ++t) sum += exp(lg[t] - m);
    importance[q] = (float)(1.0 / sum);  // max softmax = 1/sum
  }
}

// ---------------------------------------------------------------------------
// Kernel 5: softmax over Lq per batch, write reconstructed query (f64 internal).
__global__ __launch_bounds__(128) void out_kernel(const float* __restrict__ importance,
                                                  const int* __restrict__ qtok,
                                                  float* __restrict__ out) {
  const int b = blockIdx.x, i = threadIdx.x;  // 4 blocks x 128 threads
  __shared__ double sred[2];
  const double v = (double)importance[b * 128 + i];
  double m = v;
#pragma unroll
  for (int off = 32; off; off >>= 1) m = fmax(m, __shfl_xor(m, off, 64));
  if ((i & 63) == 0) sred[i >> 6] = m;
  __syncthreads();
  const double M = fmax(sred[0], sred[1]);
  const double e = exp(v - M);
  double s = e;
#pragma unroll
  for (int off = 32; off; off >>= 1) s += __shfl_xor(s, off, 64);
  __syncthreads();
  if ((i & 63) == 0) sred[i >> 6] = s;
  __syncthreads();
  const double S = sred[0] + sred[1];
  out[b * 128 + i] = (float)((double)qtok[b * 128 + i] * (e / S) * 128.0);
}

// ---------------------------------------------------------------------------
extern "C" void kernel_launch(void* const* d_in, const int* in_sizes, int n_in,
                              void* d_out, int out_size, void* d_ws, size_t ws_size,
                              hipStream_t stream) {
  const int* qtok = (const int*)d_in[0];
  const int* ctok = (const int*)d_in[1];
  const float* emb = (const float*)d_in[2];
  const float* W = (const float*)d_in[3];
  const float* bvec = (const float*)d_in[4];
  float* out = (float*)d_out;

  char* ws = (char*)d_ws;
  float* cn2 = (float*)ws;                               // 256 KB
  float* qp = cn2 + LCTX;                                // 256 KB
  float* imp = qp + (size_t)NQ * D;                      // 2 KB
  unsigned short* cemb = (unsigned short*)(imp + NQ);    // 16.9 MB (16B-aligned)
  float2* partials = (float2*)(cemb + (size_t)NROWS * D);// 8.4 MB
  // total ws ~= 25.8 MB

  pack_kernel<<<NROWS / 8, 256, 0, stream>>>(ctok, qtok, emb, cemb, cn2);
  qprep_kernel<<<NQ / 8, 256, 0, stream>>>(qtok, emb, W, bvec, qp);
  dist_topk_kernel<<<dim3(NCH, NQT), 256, 0, stream>>>(cemb, cn2, partials);
  select_kernel<<<NQ / 4, 256, 0, stream>>>(partials, qtok, ctok, emb, qp, imp);
  out_kernel<<<4, 128, 0, stream>>>(imp, qtok, out);
}

// Round 11
// 150.848 us; speedup vs baseline: 50.4898x; 1.0490x over previous
//
#include <hip/hip_runtime.h>
#include <math.h>

// Problem constants
#define D      128
#define NQ     512          // B * LQ = 4 * 128
#define LCTX   65536
#define TOPN   8
#define NCAND  16           // coarse candidates refined in f64
// Distance-kernel tiling
#define QT     64           // queries per block (4 waves x 16)
#define CCHUNK 512          // contexts per block
#define CSTEP  128          // contexts staged per LDS step
#define NCH    (LCTX / CCHUNK)    // 128 chunks
#define PERCHUNK 16               // candidates stored per (query, chunk)
#define NCANDTOT (NCH * PERCHUNK) // 2048 coarse candidates per query
#define NQT    (NQ / QT)          // 8 query tiles
#define NROWS  (LCTX + NQ)        // packed table rows (contexts then queries)
#define FINF   3.0e38f

typedef __attribute__((ext_vector_type(8))) __bf16 bf16x8;
typedef __attribute__((ext_vector_type(4))) float f32x4;

// pack two f32 -> two bf16 (round-to-nearest-ish; coarse path only)
static __device__ __forceinline__ unsigned pack2(float a, float b) {
  const unsigned ua = (__float_as_uint(a) + 0x8000u) >> 16;
  const unsigned ub = (__float_as_uint(b) + 0x8000u) & 0xffff0000u;
  return ua | ub;
}

// ---------------------------------------------------------------------------
// Kernel 1: gather+pack ALL rows (contexts + queries) to bf16 ONCE, fused with
// ||c||^2.  cemb rows are chunk-XOR-pre-swizzled (chunk c at slot c ^ (row&7))
// so global_load_lds deposits the swizzled layout with zero shader work.
__global__ __launch_bounds__(256) void pack_kernel(const int* __restrict__ ctok,
                                                   const int* __restrict__ qtok,
                                                   const float* __restrict__ emb,
                                                   unsigned short* __restrict__ cemb,
                                                   float* __restrict__ cn2) {
  const int g = threadIdx.x >> 5, l = threadIdx.x & 31;
  const int row = blockIdx.x * 8 + g;  // grid exact: NROWS/8
  const int tok = (row < LCTX) ? ctok[row] : qtok[row - LCTX];
  const float4 v = *(const float4*)(emb + (size_t)tok * D + 4 * l);
  float p = v.x * v.x + v.y * v.y + v.z * v.z + v.w * v.w;
#pragma unroll
  for (int off = 16; off; off >>= 1) p += __shfl_xor(p, off, 32);
  if (l == 0 && row < LCTX) cn2[row] = p;
  const int c = l >> 1, h = l & 1;       // 16-B chunk, half-chunk
  const int pch = c ^ (row & 7);         // pre-swizzle
  uint2 pk = make_uint2(pack2(v.x, v.y), pack2(v.z, v.w));
  *(uint2*)(&cemb[(size_t)row * D + pch * 8 + h * 4]) = pk;
}

// ---------------------------------------------------------------------------
// Kernel 2: qp = q @ W + b.  64 blocks x 256 thr; W staged once in LDS and
// amortized over 8 queries.
__global__ __launch_bounds__(256) void qprep_kernel(const int* __restrict__ qtok,
                                                    const float* __restrict__ emb,
                                                    const float* __restrict__ W,
                                                    const float* __restrict__ bvec,
                                                    float* __restrict__ qp) {
  __shared__ float sW[D * D];   // 64 KB
  __shared__ float sq[8][D];    // 4 KB
  const int tid = threadIdx.x;
  const int qb = blockIdx.x * 8;
#pragma unroll
  for (int j = 0; j < 16; ++j) {
    const int i4 = j * 256 + tid;
    *(float4*)(&sW[i4 * 4]) = *(const float4*)(W + i4 * 4);
  }
  {
    const int r = tid >> 5, l = tid & 31;
    const int tok = qtok[qb + r];
    *(float4*)(&sq[r][4 * l]) = *(const float4*)(emb + (size_t)tok * D + 4 * l);
  }
  __syncthreads();
  const int d = tid & 127, qs = tid >> 7;  // thread handles queries qs,qs+2,qs+4,qs+6
  const float bv = bvec[d];
  float acc[4] = {bv, bv, bv, bv};
  for (int k = 0; k < D; ++k) {
    const float wv = sW[k * D + d];
#pragma unroll
    for (int i = 0; i < 4; ++i) acc[i] = fmaf(sq[2 * i + qs][k], wv, acc[i]);
  }
#pragma unroll
  for (int i = 0; i < 4; ++i) qp[(size_t)(qb + 2 * i + qs) * D + d] = acc[i];
}

// ---------------------------------------------------------------------------
// Kernel 3: coarse scores via bf16 MFMA + per-lane sorted top-4 (branchless
// v_med3_f32 ladder); 16 candidates per (query, chunk) written directly.
__global__ __launch_bounds__(256, 4) void dist_topk_kernel(
    const unsigned short* __restrict__ cemb, const float* __restrict__ cn2,
    float2* __restrict__ partials) {
  __shared__ __align__(16) unsigned short sCt[CSTEP * D];  // 32 KB
  __shared__ __align__(16) float scn2[CCHUNK];             // 2 KB

  const int tid = threadIdx.x;
  const int wid = tid >> 6, lane = tid & 63;
  const int n = lane & 15, qq = lane >> 4;   // query col, k-quad / C-row group
  const int chunk = blockIdx.x, qtile = blockIdx.y;
  const int qbase = qtile * QT, cbase0 = chunk * CCHUNK;

  scn2[tid] = cn2[cbase0 + tid];
  scn2[tid + 256] = cn2[cbase0 + tid + 256];

  // ---- stage Q tile (rows LCTX+qbase..+63) into sCt rows 0..63 via DMA ----
  {
    const unsigned short* qrowbase = cemb + (size_t)(LCTX + qbase) * D;
#pragma unroll
    for (int j = 0; j < 4; ++j) {
      const int r0 = wid * 16 + j * 4;  // 4 rows per inst (64 lanes x 16 B)
      const unsigned short* gp = qrowbase + r0 * D + lane * 8;
      __builtin_amdgcn_global_load_lds(
          (const __attribute__((address_space(1))) unsigned int*)gp,
          (__attribute__((address_space(3))) unsigned int*)&sCt[r0 * D], 16, 0, 0);
    }
  }
  __syncthreads();

  // ---- B-fragments from swizzled LDS: B[n][k=32kk+8qq+j] ----
  bf16x8 bq[4];
  {
    const int rq = wid * 16 + n;
#pragma unroll
    for (int kk = 0; kk < 4; ++kk)
      bq[kk] = *(const bf16x8*)(&sCt[rq * D + 8 * ((4 * kk + qq) ^ (rq & 7))]);
  }

  // ---- per-lane sorted top-4 (ascending; bs[3] is the acceptance bound) ----
  float bs[4] = {FINF, FINF, FINF, FINF};
  int bi[4] = {0, 0, 0, 0};

  for (int st = 0; st < CCHUNK / CSTEP; ++st) {
    const int cb = cbase0 + st * CSTEP;
    __syncthreads();  // previous step's LDS reads done in all waves
    // ---- stage 128 context rows: 8 DMA insts per wave ----
    {
      const unsigned short* crowbase = cemb + (size_t)cb * D;
#pragma unroll
      for (int j = 0; j < 8; ++j) {
        const int r0 = wid * 32 + j * 4;
        const unsigned short* gp = crowbase + r0 * D + lane * 8;
        __builtin_amdgcn_global_load_lds(
            (const __attribute__((address_space(1))) unsigned int*)gp,
            (__attribute__((address_space(3))) unsigned int*)&sCt[r0 * D], 16, 0, 0);
      }
    }
    __syncthreads();

    // ---- 8 tiles of 16 contexts: 4 MFMAs (K=128) + branchless selection ----
#pragma unroll
    for (int tt = 0; tt < 8; ++tt) {
      f32x4 acc = {0.f, 0.f, 0.f, 0.f};
      const int m = 16 * tt + n;  // LDS row; (global row)&7 == n&7
#pragma unroll
      for (int kk = 0; kk < 4; ++kk) {
        const bf16x8 af = *(const bf16x8*)(&sCt[m * D + 8 * ((4 * kk + qq) ^ (n & 7))]);
        acc = __builtin_amdgcn_mfma_f32_16x16x32_bf16(af, bq[kk], acc, 0, 0, 0);
      }
      // C/D: col=lane&15 (query), row = 4*qq + r (context within tile)
      const f32x4 cv = *(const f32x4*)(&scn2[st * CSTEP + 16 * tt + 4 * qq]);
      const int ibase = cb + 16 * tt + 4 * qq;
#pragma unroll
      for (int r = 0; r < 4; ++r) {
        const float v = fmaf(-2.f, acc[r], cv[r]);
        const int iv = ibase + r;
        const bool c0 = v < bs[0], c1 = v < bs[1], c2 = v < bs[2], c3 = v < bs[3];
        const float nb0 = fminf(bs[0], v);
        const float nb1 = __builtin_amdgcn_fmed3f(v, bs[0], bs[1]);
        const float nb2 = __builtin_amdgcn_fmed3f(v, bs[1], bs[2]);
        const float nb3 = __builtin_amdgcn_fmed3f(v, bs[2], bs[3]);
        const int ni0 = c0 ? iv : bi[0];
        const int ni1 = c1 ? (c0 ? bi[0] : iv) : bi[1];
        const int ni2 = c2 ? (c1 ? bi[1] : iv) : bi[2];
        const int ni3 = c3 ? (c2 ? bi[2] : iv) : bi[3];
        bs[0] = nb0; bs[1] = nb1; bs[2] = nb2; bs[3] = nb3;
        bi[0] = ni0; bi[1] = ni1; bi[2] = ni2; bi[3] = ni3;
      }
    }
  }

  // ---- direct write-out: 16 candidates per (query, chunk), no merge ----
  const int q = qbase + wid * 16 + n;
  float2* dst = partials + (size_t)q * NCANDTOT + chunk * PERCHUNK + qq * 4;
#pragma unroll
  for (int t = 0; t < 4; ++t)
    dst[t] = make_float2(bs[t], __int_as_float(bi[t]));
}

// ---------------------------------------------------------------------------
// Kernel 4 (fused merge + f64 refine + final): ONE BLOCK (4 waves) per query.
// R10 post-mortem: the 1-wave-per-query version ran 128 blocks on 256 CUs
// (half idle, 4.7% occupancy) and serially chewed 2048 candidates -> 45.7 us.
// Phase 1a: each wave reduces 512 candidates (8/lane, its full register set —
// no pre-selection loss) to a wave top-16 via 16-round shfl argmin.
// Phase 1b: wave 0 reduces the 64 survivors (1/lane) to the exact top-16.
// Phase 2: f64 refine across all 256 threads (16 lanes x 8 dims per cand).
// Phase 3: thread 0 serial exact top-8-of-16 + logits + max-softmax (f64).
__global__ __launch_bounds__(256) void select_kernel(
    const float2* __restrict__ partials, const int* __restrict__ qtok,
    const int* __restrict__ ctok, const float* __restrict__ emb,
    const float* __restrict__ qp, float* __restrict__ importance) {
  __shared__ float2 swt[64];                 // 4 waves x 16 wave-top cands
  __shared__ double sd2[NCAND], sdp[NCAND];
  __shared__ int sid[NCAND];
  const int tid = threadIdx.x;
  const int w = tid >> 6, lane = tid & 63;
  const int q = blockIdx.x;

  // ---- phase 1a: per-wave top-16 of 512 ----
  float v[8]; int vi[8];
  const float2* pq = partials + (size_t)q * NCANDTOT;
#pragma unroll
  for (int j = 0; j < 8; ++j) {
    const float2 cd = pq[256 * j + tid];  // coalesced 2KB per block-load
    v[j] = cd.x; vi[j] = __float_as_int(cd.y);
  }
  unsigned consumed = 0;
#pragma unroll
  for (int t = 0; t < NCAND; ++t) {
    float lmin = FINF; int li = 0x7fffffff; int ls = 0;
#pragma unroll
    for (int j = 0; j < 8; ++j) {
      const bool take = !((consumed >> j) & 1u) && (v[j] < lmin);
      lmin = take ? v[j] : lmin;
      li = take ? vi[j] : li;
      ls = take ? j : ls;
    }
    float m = lmin; int pidx = li; int pwho = (lane << 3) | ls;
#pragma unroll
    for (int off = 32; off; off >>= 1) {
      const float om = __shfl_xor(m, off, 64);
      const int oi = __shfl_xor(pidx, off, 64);
      const int ow = __shfl_xor(pwho, off, 64);
      const bool better = (om < m) || (om == m && oi < pidx);
      m = better ? om : m; pidx = better ? oi : pidx; pwho = better ? ow : pwho;
    }
    if ((pwho >> 3) == lane) consumed |= 1u << (pwho & 7);
    if (lane == t) swt[w * 16 + t] = make_float2(m, __int_as_float(pidx));
  }
  __syncthreads();

  // ---- phase 1b: wave 0 takes top-16 of the 64 wave-survivors ----
  if (w == 0) {
    const float2 cd = swt[lane];
    const float mv = cd.x; const int mi = __float_as_int(cd.y);
    bool cons = false;
#pragma unroll
    for (int t = 0; t < NCAND; ++t) {
      float m = cons ? FINF : mv;
      int pidx = cons ? 0x7fffffff : mi;
      int pwho = lane;
#pragma unroll
      for (int off = 32; off; off >>= 1) {
        const float om = __shfl_xor(m, off, 64);
        const int oi = __shfl_xor(pidx, off, 64);
        const int ow = __shfl_xor(pwho, off, 64);
        const bool better = (om < m) || (om == m && oi < pidx);
        m = better ? om : m; pidx = better ? oi : pidx; pwho = better ? ow : pwho;
      }
      if (pwho == lane) cons = true;
      if (lane == t) sid[t] = pidx;
    }
  }
  __syncthreads();

  // ---- phase 2: f64 refine; cand c = tid>>4, 8 dims per lane ----
  const int c = tid >> 4, sub = tid & 15;
  const int idx = sid[c];
  const int tc = ctok[idx];
  const int tq = qtok[q];
  const float* crow = emb + (size_t)tc * D + sub * 8;
  const float* qrow = emb + (size_t)tq * D + sub * 8;
  const float* prow = qp + (size_t)q * D + sub * 8;
  double dd = 0.0, pp = 0.0;
#pragma unroll
  for (int kk = 0; kk < 2; ++kk) {
    const float4 cv = *(const float4*)(crow + 4 * kk);
    const float4 qv = *(const float4*)(qrow + 4 * kk);
    const float4 pv = *(const float4*)(prow + 4 * kk);
    const double dx = (double)qv.x - (double)cv.x, dy = (double)qv.y - (double)cv.y;
    const double dz = (double)qv.z - (double)cv.z, dw = (double)qv.w - (double)cv.w;
    dd += dx * dx + dy * dy + dz * dz + dw * dw;
    pp += (double)pv.x * (double)cv.x + (double)pv.y * (double)cv.y +
          (double)pv.z * (double)cv.z + (double)pv.w * (double)cv.w;
  }
  // reduce within the aligned 16-lane group
#pragma unroll
  for (int off = 1; off <= 8; off <<= 1) {
    dd += __shfl_xor(dd, off, 64);
    pp += __shfl_xor(pp, off, 64);
  }
  if (sub == 0) { sd2[c] = dd; sdp[c] = pp; }
  __syncthreads();

  // ---- phase 3: thread 0 serial exact top-8 + logits + max-softmax ----
  if (tid == 0) {
    bool used[NCAND];
#pragma unroll
    for (int n2 = 0; n2 < NCAND; ++n2) used[n2] = false;
    double lg[TOPN];
    for (int t = 0; t < TOPN; ++t) {
      int best = -1;
      for (int n2 = 0; n2 < NCAND; ++n2) {
        if (used[n2]) continue;
        if (best < 0 || sd2[n2] < sd2[best] ||
            (sd2[n2] == sd2[best] && sid[n2] < sid[best])) best = n2;
      }
      used[best] = true;
      lg[t] = sdp[best] * 0.08838834764831843 - sqrt(sd2[best] + 1e-12);
    }
    double m = lg[0];
#pragma unroll
    for (int t = 1; t < TOPN; ++t) m = fmax(m, lg[t]);
    double sum = 0.0;
#pragma unroll
    for (int t = 0; t < TOPN; ++t) sum += exp(lg[t] - m);
    importance[q] = (float)(1.0 / sum);  // max softmax = 1/sum
  }
}

// ---------------------------------------------------------------------------
// Kernel 5: softmax over Lq per batch, write reconstructed query (f64 internal).
__global__ __launch_bounds__(128) void out_kernel(const float* __restrict__ importance,
                                                  const int* __restrict__ qtok,
                                                  float* __restrict__ out) {
  const int b = blockIdx.x, i = threadIdx.x;  // 4 blocks x 128 threads
  __shared__ double sred[2];
  const double v = (double)importance[b * 128 + i];
  double m = v;
#pragma unroll
  for (int off = 32; off; off >>= 1) m = fmax(m, __shfl_xor(m, off, 64));
  if ((i & 63) == 0) sred[i >> 6] = m;
  __syncthreads();
  const double M = fmax(sred[0], sred[1]);
  const double e = exp(v - M);
  double s = e;
#pragma unroll
  for (int off = 32; off; off >>= 1) s += __shfl_xor(s, off, 64);
  __syncthreads();
  if ((i & 63) == 0) sred[i >> 6] = s;
  __syncthreads();
  const double S = sred[0] + sred[1];
  out[b * 128 + i] = (float)((double)qtok[b * 128 + i] * (e / S) * 128.0);
}

// ---------------------------------------------------------------------------
extern "C" void kernel_launch(void* const* d_in, const int* in_sizes, int n_in,
                              void* d_out, int out_size, void* d_ws, size_t ws_size,
                              hipStream_t stream) {
  const int* qtok = (const int*)d_in[0];
  const int* ctok = (const int*)d_in[1];
  const float* emb = (const float*)d_in[2];
  const float* W = (const float*)d_in[3];
  const float* bvec = (const float*)d_in[4];
  float* out = (float*)d_out;

  char* ws = (char*)d_ws;
  float* cn2 = (float*)ws;                               // 256 KB
  float* qp = cn2 + LCTX;                                // 256 KB
  float* imp = qp + (size_t)NQ * D;                      // 2 KB
  unsigned short* cemb = (unsigned short*)(imp + NQ);    // 16.9 MB (16B-aligned)
  float2* partials = (float2*)(cemb + (size_t)NROWS * D);// 8.4 MB
  // total ws ~= 25.8 MB

  pack_kernel<<<NROWS / 8, 256, 0, stream>>>(ctok, qtok, emb, cemb, cn2);
  qprep_kernel<<<NQ / 8, 256, 0, stream>>>(qtok, emb, W, bvec, qp);
  dist_topk_kernel<<<dim3(NCH, NQT), 256, 0, stream>>>(cemb, cn2, partials);
  select_kernel<<<NQ, 256, 0, stream>>>(partials, qtok, ctok, emb, qp, imp);
  out_kernel<<<4, 128, 0, stream>>>(imp, qtok, out);
}